// Round 4
// baseline (1690.059 us; speedup 1.0000x reference)
//
#include <hip/hip_runtime.h>
#include <math.h>

#define SS 128
#define BB 32
#define CC 16
#define DW 256
#define DC 64
#define HC 128
#define KX 384   // DW + HC
#define TT 17

typedef __attribute__((ext_vector_type(8))) short bf16x8;
typedef __attribute__((ext_vector_type(4))) float f32x4;
typedef unsigned long long ull_t;

__device__ __forceinline__ float sigf(float x) { return 1.0f / (1.0f + __expf(-x)); }
__device__ __forceinline__ float tanhfast(float x) {
  float xc = fminf(fmaxf(x, -15.f), 15.f);
  float e = __expf(2.f * xc);
  return (e - 1.f) / (e + 1.f);
}
__device__ __forceinline__ unsigned short f2bf(float x) {
  unsigned int u = __float_as_uint(x);
  u += 0x7FFF + ((u >> 16) & 1);
  return (unsigned short)(u >> 16);
}

// ---------------------------------------------------------------- K0: char ih vocab table
__global__ __launch_bounds__(256) void k0_ihvocab(
    const float* __restrict__ Wce,
    const float* __restrict__ WihF, const float* __restrict__ bF,
    const float* __restrict__ WihB, const float* __restrict__ bB,
    float* __restrict__ ihv) {
  int blk = blockIdx.x;          // 0..199
  int d = blk / 100, v = blk % 100;
  const float* Wih = d ? WihB : WihF;
  const float* bb  = d ? bB   : bF;
  __shared__ float ce[DC];
  if (threadIdx.x < DC) ce[threadIdx.x] = Wce[v * DC + threadIdx.x];
  __syncthreads();
  int g = threadIdx.x;
  float acc = bb[g];
  #pragma unroll 16
  for (int k = 0; k < DC; ++k) acc += ce[k] * Wih[g * DC + k];
  ihv[(d * 100 + v) * 256 + g] = acc;
}

// ---------------------------------------------------------------- K1: char BiLSTM (per-chain, no global sync)
__global__ __launch_bounds__(256) void k1_char(
    const int* __restrict__ charidx,   // (B,S,C)
    const float* __restrict__ WhhF, const float* __restrict__ WhhB,
    const float* __restrict__ ihv,     // (2,100,256)
    float* __restrict__ x)             // (4096, 384)
{
  int blk = blockIdx.x;
  int d = blk >> 8;
  int n0 = (blk & 255) * 16;
  const float* Whh = d ? WhhB : WhhF;

  __shared__ float Wl[256 * 68];
  __shared__ float hl[16 * 68];

  for (int i = threadIdx.x; i < 256 * 64; i += 256) {
    int g = i >> 6, k = i & 63;
    Wl[g * 68 + k] = Whh[i];
  }
  __syncthreads();

  int hh = threadIdx.x & 63;
  int ng = threadIdx.x >> 6;
  float c[4] = {0.f, 0.f, 0.f, 0.f};
  float h[4] = {0.f, 0.f, 0.f, 0.f};
  int bb_[4], ss_[4];
  #pragma unroll
  for (int m = 0; m < 4; ++m) {
    int n = n0 + ng + 4 * m;
    bb_[m] = n >> 7; ss_[m] = n & 127;
  }

  for (int t = 0; t < CC; ++t) {
    int cpos = d ? (CC - 1 - t) : t;
    float acc[4][4];
    #pragma unroll
    for (int m = 0; m < 4; ++m) {
      int v = charidx[bb_[m] * (SS * CC) + ss_[m] * CC + cpos];
      const float* base = ihv + (d * 100 + v) * 256 + hh;
      acc[m][0] = base[0]; acc[m][1] = base[64]; acc[m][2] = base[128]; acc[m][3] = base[192];
    }
    if (t > 0) {
      #pragma unroll 4
      for (int k = 0; k < 64; k += 4) {
        float4 w4[4];
        #pragma unroll
        for (int q = 0; q < 4; ++q)
          w4[q] = *(const float4*)&Wl[(q * 64 + hh) * 68 + k];
        #pragma unroll
        for (int m = 0; m < 4; ++m) {
          float4 h4 = *(const float4*)&hl[(ng + 4 * m) * 68 + k];
          #pragma unroll
          for (int q = 0; q < 4; ++q)
            acc[m][q] += h4.x * w4[q].x + h4.y * w4[q].y + h4.z * w4[q].z + h4.w * w4[q].w;
        }
      }
      __syncthreads();
    }
    #pragma unroll
    for (int m = 0; m < 4; ++m) {
      float ig = sigf(acc[m][0]);
      float fg = sigf(acc[m][1]);
      float gg = tanhfast(acc[m][2]);
      float og = sigf(acc[m][3]);
      c[m] = fg * c[m] + ig * gg;
      h[m] = og * tanhfast(c[m]);
      hl[(ng + 4 * m) * 68 + hh] = h[m];
    }
    __syncthreads();
  }
  #pragma unroll
  for (int m = 0; m < 4; ++m) {
    int row = ss_[m] * BB + bb_[m];
    x[row * KX + d * 64 + hh] = h[m];
  }
}

// ---------------------------------------------------------------- K2: word embedding gather
__global__ __launch_bounds__(64) void k2_we(
    const int* __restrict__ sentence, const float* __restrict__ Wwe,
    float* __restrict__ x) {
  int row = blockIdx.x;
  int idx = sentence[row];
  const float4* src = (const float4*)(Wwe + (size_t)idx * DW);
  float4* dst = (float4*)(x + (size_t)row * KX + HC);
  dst[threadIdx.x] = src[threadIdx.x];
}

// ---------------------------------------------------------------- K3: word ih GEMM  wg[d][row][g]
__global__ __launch_bounds__(256) void k3_ihgemm(
    const float* __restrict__ x,
    const float* __restrict__ WihF, const float* __restrict__ bF,
    const float* __restrict__ WihB, const float* __restrict__ bB,
    float* __restrict__ wg) {
  int n0 = blockIdx.x * 128;
  int m0 = blockIdx.y * 128;
  int d  = n0 >> 10;
  int gb = n0 & 1023;
  const float* Wih  = d ? WihB : WihF;
  const float* bias = d ? bB   : bF;

  __shared__ float At[32][132];
  __shared__ float Bt[32][132];

  int tid = threadIdx.x;
  int half = tid & 1, r = tid >> 1;
  int tm = tid & 15, tn = tid >> 4;
  float acc[8][8] = {};

  for (int k0 = 0; k0 < KX; k0 += 32) {
    __syncthreads();
    {
      const float4* srcA = (const float4*)(x + (size_t)(m0 + r) * KX + k0 + half * 16);
      const float4* srcB = (const float4*)(Wih + (size_t)(gb + r) * KX + k0 + half * 16);
      #pragma unroll
      for (int q = 0; q < 4; ++q) {
        float4 v = srcA[q];
        int kk = half * 16 + q * 4;
        At[kk + 0][r] = v.x; At[kk + 1][r] = v.y; At[kk + 2][r] = v.z; At[kk + 3][r] = v.w;
      }
      #pragma unroll
      for (int q = 0; q < 4; ++q) {
        float4 v = srcB[q];
        int kk = half * 16 + q * 4;
        Bt[kk + 0][r] = v.x; Bt[kk + 1][r] = v.y; Bt[kk + 2][r] = v.z; Bt[kk + 3][r] = v.w;
      }
    }
    __syncthreads();
    #pragma unroll 8
    for (int k = 0; k < 32; ++k) {
      float4 a0 = *(const float4*)&At[k][tm * 8];
      float4 a1 = *(const float4*)&At[k][tm * 8 + 4];
      float4 b0 = *(const float4*)&Bt[k][tn * 8];
      float4 b1 = *(const float4*)&Bt[k][tn * 8 + 4];
      float av[8] = {a0.x, a0.y, a0.z, a0.w, a1.x, a1.y, a1.z, a1.w};
      float bv[8] = {b0.x, b0.y, b0.z, b0.w, b1.x, b1.y, b1.z, b1.w};
      #pragma unroll
      for (int i = 0; i < 8; ++i)
        #pragma unroll
        for (int jq = 0; jq < 8; ++jq)
          acc[i][jq] += av[i] * bv[jq];
    }
  }
  float bv8[8];
  #pragma unroll
  for (int jq = 0; jq < 8; ++jq) bv8[jq] = bias[gb + tn * 8 + jq];
  #pragma unroll
  for (int i = 0; i < 8; ++i) {
    int m = m0 + tm * 8 + i;
    float* dst = wg + ((size_t)(d * 4096 + m)) * 1024 + gb + tn * 8;
    float4 v0 = {acc[i][0] + bv8[0], acc[i][1] + bv8[1], acc[i][2] + bv8[2], acc[i][3] + bv8[3]};
    float4 v1 = {acc[i][4] + bv8[4], acc[i][5] + bv8[5], acc[i][6] + bv8[6], acc[i][7] + bv8[7]};
    *(float4*)dst = v0; *(float4*)(dst + 4) = v1;
  }
}

// ---------------------------------------------------------------- K3b: pack streamed Whh quarter (ch=1, ks=4..7) as bf16 frags
// Layout: wstr[((d*8 + w)*16 + q*4 + (ks-4)) * 512 + lane*8] (shorts).
__global__ __launch_bounds__(64) void k3b_pack(
    const float* __restrict__ WhhF, const float* __restrict__ WhhB,
    unsigned short* __restrict__ wstr) {
  int bid = blockIdx.x;            // 0..255
  int d = bid >> 7;
  int rem = bid & 127;             // w*16 + fidx
  int w = rem >> 4, fidx = rem & 15;
  int q = fidx >> 2, ks = (fidx & 3) + 4;
  const float* Whh = d ? WhhB : WhhF;
  int l = threadIdx.x, l15 = l & 15, q4 = l >> 4;
  const float* wr = Whh + (size_t)(q * 256 + w * 32 + 16 + l15) * 256 + ks * 32 + q4 * 8;
  float4 lo = *(const float4*)(wr);
  float4 hi = *(const float4*)(wr + 4);
  bf16x8 f;
  f[0] = (short)f2bf(lo.x); f[1] = (short)f2bf(lo.y);
  f[2] = (short)f2bf(lo.z); f[3] = (short)f2bf(lo.w);
  f[4] = (short)f2bf(hi.x); f[5] = (short)f2bf(hi.y);
  f[6] = (short)f2bf(hi.z); f[7] = (short)f2bf(hi.w);
  *(bf16x8*)(wstr + (size_t)(bid * 512 + l * 8)) = f;
}

// ---------------------------------------------------------------- K4: word BiLSTM recurrence (batch-split, barrier-synced)
// 4 WGs = 2 dir x 2 batch-halves; each WG: 8 waves x 512 thr, owns 16 batches
// and ALL 256 h-cols. Wave w owns cols j0=w*32..+31 x 4 gates (N=128, M=16,
// K=256 -> 64 MFMA 16x16x32 per wave per step). h exchange: LDS + 1 barrier
// per step. Whh per wave (64KB bf16): 32 frags resident VGPR (ch=0), 16 in
// LDS (ch=1 ks0..3), 16 streamed from L2 each step (ch=1 ks4..7, prepacked).
// No atomics, no cross-WG traffic. 147KB LDS/WG -> exclusive CU per WG.
//
// VGPR budget: rounds 2/3 both compiled at a 128-VGPR cap (hipcc default
// occupancy heuristic; launch_bounds can't raise it) -> the 128-reg Bf
// weight array spilled -> 9.1us/step. amdgpu_waves_per_eu(2,2) targets
// exactly 2 waves/EU (= the 1-block/CU reality of a 512-thr 147KB-LDS WG)
// -> 256-VGPR cap -> Bf stays resident. Verification signal: VGPR_Count~256.
__global__ __attribute__((amdgpu_waves_per_eu(2, 2))) __launch_bounds__(512)
void k4_word(
    const float* __restrict__ WhhF, const float* __restrict__ WhhB,
    const float* __restrict__ wg,           // (2,4096,1024) f32
    float* __restrict__ outh,               // (4096,512) f32
    const unsigned short* __restrict__ wstr) {
  const int blk = blockIdx.x;               // 0..3
  const int d = blk >> 1, half = blk & 1;
  const int tid = threadIdx.x;
  const int w = tid >> 6;                   // wave 0..7
  const int l = tid & 63;
  const int l15 = l & 15, q4 = l >> 4;
  const int j0 = w * 32;
  const float* __restrict__ Whh = d ? WhhB : WhhF;

  __shared__ unsigned short ldsw[8 * 16 * 64 * 8];   // 131072 B: weight frags
  __shared__ unsigned short hsh[2 * 16 * 256];       // 16384 B: h double-buffer (swizzled)

  // ---- resident Bf: ch=0 (cols j0..j0+15), q=0..3, ks=0..7
  bf16x8 Bf[4][8];
  #pragma unroll
  for (int q = 0; q < 4; ++q) {
    const float* wr = Whh + (size_t)(q * 256 + j0 + l15) * 256 + q4 * 8;
    #pragma unroll
    for (int ks = 0; ks < 8; ++ks) {
      float4 lo = *(const float4*)(wr + ks * 32);
      float4 hi = *(const float4*)(wr + ks * 32 + 4);
      bf16x8 f;
      f[0] = (short)f2bf(lo.x); f[1] = (short)f2bf(lo.y);
      f[2] = (short)f2bf(lo.z); f[3] = (short)f2bf(lo.w);
      f[4] = (short)f2bf(hi.x); f[5] = (short)f2bf(hi.y);
      f[6] = (short)f2bf(hi.z); f[7] = (short)f2bf(hi.w);
      Bf[q][ks] = f;
    }
  }
  // ---- LDS weights: ch=1 (cols j0+16..j0+31), ks=0..3 (one-time, wave-own)
  #pragma unroll
  for (int q = 0; q < 4; ++q) {
    const float* wr = Whh + (size_t)(q * 256 + j0 + 16 + l15) * 256 + q4 * 8;
    #pragma unroll
    for (int ks = 0; ks < 4; ++ks) {
      float4 lo = *(const float4*)(wr + ks * 32);
      float4 hi = *(const float4*)(wr + ks * 32 + 4);
      bf16x8 f;
      f[0] = (short)f2bf(lo.x); f[1] = (short)f2bf(lo.y);
      f[2] = (short)f2bf(lo.z); f[3] = (short)f2bf(lo.w);
      f[4] = (short)f2bf(hi.x); f[5] = (short)f2bf(hi.y);
      f[6] = (short)f2bf(hi.z); f[7] = (short)f2bf(hi.w);
      *(bf16x8*)&ldsw[((w * 16 + q * 4 + ks) * 64 + l) * 8] = f;
    }
  }

  const unsigned short* sbase = wstr + (size_t)(d * 8 + w) * 8192;  // 16 frags * 512 shorts

  f32x4 acc[4][2];
  float cst[8];
  #pragma unroll
  for (int i = 0; i < 8; ++i) cst[i] = 0.f;

  // ---- prologue: gates for t=0
  {
    const int s0 = d ? (SS - 1) : 0;
    const float* wgs = wg + ((size_t)d * 4096 + (size_t)s0 * 32 + half * 16) * 1024 + j0 + l15;
    #pragma unroll
    for (int q = 0; q < 4; ++q)
      #pragma unroll
      for (int ch = 0; ch < 2; ++ch)
        #pragma unroll
        for (int r = 0; r < 4; ++r)
          acc[q][ch][r] = wgs[(size_t)(q4 * 4 + r) * 1024 + q * 256 + ch * 16];
  }

  bf16x8 Sb[8];
  for (int t = 0; t < SS; ++t) {
    const int s = d ? (SS - 1 - t) : t;

    if (t > 0) {
      // ---- issue stream chunk A (q=0,1 | ch1 | ks4..7) pre-barrier
      #pragma unroll
      for (int i = 0; i < 8; ++i)
        Sb[i] = *(const bf16x8*)(sbase + i * 512 + l * 8);
      __syncthreads();
      const int pr = ((t - 1) & 1) * 4096;
      // ---- khalf0: Af ks0..3, resident + LDS weights
      bf16x8 Af0[4];
      #pragma unroll
      for (int ks = 0; ks < 4; ++ks)
        Af0[ks] = *(const bf16x8*)&hsh[pr + l15 * 256 + (((ks * 4 + q4) ^ (l15 & 7)) * 8)];
      #pragma unroll
      for (int q = 0; q < 4; ++q) {
        #pragma unroll
        for (int ks = 0; ks < 4; ++ks)
          acc[q][0] = __builtin_amdgcn_mfma_f32_16x16x32_bf16(Af0[ks], Bf[q][ks], acc[q][0], 0, 0, 0);
        #pragma unroll
        for (int ks = 0; ks < 4; ++ks) {
          bf16x8 bw = *(const bf16x8*)&ldsw[((w * 16 + q * 4 + ks) * 64 + l) * 8];
          acc[q][1] = __builtin_amdgcn_mfma_f32_16x16x32_bf16(Af0[ks], bw, acc[q][1], 0, 0, 0);
        }
      }
      // ---- issue stream chunk B (q=2,3 | ch1 | ks4..7); hidden under khalf1
      bf16x8 Sb2[8];
      #pragma unroll
      for (int i = 0; i < 8; ++i)
        Sb2[i] = *(const bf16x8*)(sbase + (8 + i) * 512 + l * 8);
      // ---- khalf1: Af ks4..7, resident + streamed
      bf16x8 Af1[4];
      #pragma unroll
      for (int ks = 0; ks < 4; ++ks)
        Af1[ks] = *(const bf16x8*)&hsh[pr + l15 * 256 + ((((ks + 4) * 4 + q4) ^ (l15 & 7)) * 8)];
      #pragma unroll
      for (int q = 0; q < 4; ++q)
        #pragma unroll
        for (int ks = 0; ks < 4; ++ks)
          acc[q][0] = __builtin_amdgcn_mfma_f32_16x16x32_bf16(Af1[ks], Bf[q][ks + 4], acc[q][0], 0, 0, 0);
      #pragma unroll
      for (int q = 0; q < 2; ++q)
        #pragma unroll
        for (int kk = 0; kk < 4; ++kk)
          acc[q][1] = __builtin_amdgcn_mfma_f32_16x16x32_bf16(Af1[kk], Sb[q * 4 + kk], acc[q][1], 0, 0, 0);
      #pragma unroll
      for (int q = 2; q < 4; ++q)
        #pragma unroll
        for (int kk = 0; kk < 4; ++kk)
          acc[q][1] = __builtin_amdgcn_mfma_f32_16x16x32_bf16(Af1[kk], Sb2[(q - 2) * 4 + kk], acc[q][1], 0, 0, 0);
    }

    // ---- activations; lane owns (b = half*16 + q4*4+r, col = j0 + ch*16 + l15)
    float hv[8];
    #pragma unroll
    for (int ch = 0; ch < 2; ++ch)
      #pragma unroll
      for (int r = 0; r < 4; ++r) {
        int ix = ch * 4 + r;
        float ig = sigf(acc[0][ch][r]);
        float fg = sigf(acc[1][ch][r]);
        float gg = tanhfast(acc[2][ch][r]);
        float og = sigf(acc[3][ch][r]);
        float c2 = fg * cst[ix] + ig * gg;
        cst[ix] = c2;
        hv[ix] = og * tanhfast(c2);
      }

    // ---- gates for t+1 (issued early; HBM latency hides under barrier+Af+MFMA)
    if (t < SS - 1) {
      const int sn = d ? (SS - 2 - t) : (t + 1);
      const float* wgs = wg + ((size_t)d * 4096 + (size_t)sn * 32 + half * 16) * 1024 + j0 + l15;
      #pragma unroll
      for (int q = 0; q < 4; ++q)
        #pragma unroll
        for (int ch = 0; ch < 2; ++ch)
          #pragma unroll
          for (int r = 0; r < 4; ++r)
            acc[q][ch][r] = wgs[(size_t)(q4 * 4 + r) * 1024 + q * 256 + ch * 16];
    }

    // ---- publish h_t to LDS (swizzled: 16B-unit ^= row&7)
    {
      const int p = (t & 1) * 4096;
      #pragma unroll
      for (int ch = 0; ch < 2; ++ch)
        #pragma unroll
        for (int r = 0; r < 4; ++r) {
          int b = q4 * 4 + r;
          int col = j0 + ch * 16 + l15;
          hsh[p + b * 256 + (((col >> 3) ^ (b & 7)) * 8) + (col & 7)] = f2bf(hv[ch * 4 + r]);
        }
    }

    // ---- outh (non-temporal, off critical path)
    {
      float* op = outh + ((size_t)(s * 32 + half * 16)) * 512 + d * 256 + j0 + l15;
      #pragma unroll
      for (int ch = 0; ch < 2; ++ch)
        #pragma unroll
        for (int r = 0; r < 4; ++r)
          __builtin_nontemporal_store(hv[ch * 4 + r], op + (size_t)(q4 * 4 + r) * 512 + ch * 16);
    }
  }
}

// ---------------------------------------------------------------- K5: emit GEMM (tiny)
__global__ __launch_bounds__(64) void k5_emit(
    const float* __restrict__ outh, const float* __restrict__ eW,
    const float* __restrict__ eb, float* __restrict__ em) {
  int row = blockIdx.x;
  int t = threadIdx.x;
  if (t < TT) {
    const float4* o4 = (const float4*)(outh + (size_t)row * 512);
    const float4* w4 = (const float4*)(eW + (size_t)t * 512);
    float acc = 0.f;
    #pragma unroll 16
    for (int k = 0; k < 128; ++k) {
      float4 a = o4[k], bq = w4[k];
      acc += a.x * bq.x + a.y * bq.y + a.z * bq.z + a.w * bq.w;
    }
    em[row * TT + t] = acc + eb[t];
  }
}

// ---------------------------------------------------------------- K6: CRF NLL (32 independent batches)
__global__ __launch_bounds__(64) void k6_crf(
    const int* __restrict__ sentence, const int* __restrict__ tags,
    const float* __restrict__ em, const float* __restrict__ trans,
    const float* __restrict__ startv, const float* __restrict__ endv,
    float* __restrict__ outp) {
  int b = blockIdx.x;
  int j = threadIdx.x;
  __shared__ float ash[TT];
  __shared__ float red[TT];
  float tc[TT];
  float alpha = 0.f;
  if (j < TT) {
    #pragma unroll
    for (int i = 0; i < TT; ++i) tc[i] = trans[i * TT + j];
    alpha = startv[j] + em[(0 * BB + b) * TT + j];
  }
  for (int s = 1; s < SS; ++s) {
    if (j < TT) ash[j] = alpha;
    __syncthreads();
    int m = (sentence[s * BB + b] != 1) ? 1 : 0;
    if (j < TT) {
      float mx = -1e30f;
      #pragma unroll
      for (int i = 0; i < TT; ++i) mx = fmaxf(mx, ash[i] + tc[i]);
      float sum = 0.f;
      #pragma unroll
      for (int i = 0; i < TT; ++i) sum += __expf(ash[i] + tc[i] - mx);
      float nxt = mx + __logf(sum) + em[(s * BB + b) * TT + j];
      if (m) alpha = nxt;
    }
    __syncthreads();
  }
  if (j < TT) red[j] = alpha + endv[j];
  __syncthreads();
  if (j == 0) {
    float mx = -1e30f;
    for (int i = 0; i < TT; ++i) mx = fmaxf(mx, red[i]);
    float sum = 0.f;
    for (int i = 0; i < TT; ++i) sum += __expf(red[i] - mx);
    float den = mx + __logf(sum);
    int prev = tags[0 * BB + b];
    float num = startv[prev] + em[(0 * BB + b) * TT + prev];
    for (int s = 1; s < SS; ++s) {
      int tg = tags[s * BB + b];
      if (sentence[s * BB + b] != 1) {
        num += trans[prev * TT + tg] + em[(s * BB + b) * TT + tg];
        prev = tg;
      }
    }
    num += endv[prev];
    atomicAdd(outp, den - num);
  }
}

// ---------------------------------------------------------------- launcher
extern "C" void kernel_launch(void* const* d_in, const int* in_sizes, int n_in,
                              void* d_out, int out_size, void* d_ws, size_t ws_size,
                              hipStream_t stream) {
  (void)in_sizes; (void)n_in; (void)out_size; (void)ws_size;
  const int*   sentence = (const int*)d_in[0];
  const int*   charidx  = (const int*)d_in[1];
  const int*   tags     = (const int*)d_in[2];
  const float* Wwe   = (const float*)d_in[3];
  const float* Wce   = (const float*)d_in[4];
  const float* cWihF = (const float*)d_in[5];
  const float* cWhhF = (const float*)d_in[6];
  const float* cbF   = (const float*)d_in[7];
  const float* wWihF = (const float*)d_in[8];
  const float* wWhhF = (const float*)d_in[9];
  const float* wbF   = (const float*)d_in[10];
  const float* cWihB = (const float*)d_in[11];
  const float* cWhhB = (const float*)d_in[12];
  const float* cbB   = (const float*)d_in[13];
  const float* wWihB = (const float*)d_in[14];
  const float* wWhhB = (const float*)d_in[15];
  const float* wbB   = (const float*)d_in[16];
  const float* eW    = (const float*)d_in[17];
  const float* eb    = (const float*)d_in[18];
  const float* trans = (const float*)d_in[19];
  const float* startv= (const float*)d_in[20];
  const float* endv  = (const float*)d_in[21];

  char* ws = (char*)d_ws;
  float*          ihv   = (float*)(ws + 512);             //  204800 B
  float*          x     = (float*)(ws + 205312);          // 6291456 B
  float*          wg    = (float*)(ws + 6496768);         // 33554432 B
  float*          outh  = (float*)(ws + 40116736);        // 8388608 B
  float*          em    = (float*)(ws + 48505344);        //  278528 B
  // wstr (262144 B) aliases the head of the em region: em is written only by
  // k5 (after k4 completes), so the packed stream-weight buffer is dead by then.
  unsigned short* wstr  = (unsigned short*)(ws + 48505344);
  // total ws usage: 48,783,872 B (unchanged)

  hipMemsetAsync(d_out, 0, sizeof(float), stream);

  k3b_pack<<<256, 64, 0, stream>>>(wWhhF, wWhhB, wstr);
  k0_ihvocab<<<200, 256, 0, stream>>>(Wce, cWihF, cbF, cWihB, cbB, ihv);
  k1_char<<<512, 256, 0, stream>>>(charidx, cWhhF, cWhhB, ihv, x);
  k2_we<<<4096, 64, 0, stream>>>(sentence, Wwe, x);
  k3_ihgemm<<<dim3(16, 32), 256, 0, stream>>>(x, wWihF, wbF, wWihB, wbB, wg);
  k4_word<<<4, 512, 0, stream>>>(wWhhF, wWhhB, wg, outh, wstr);
  k5_emit<<<4096, 64, 0, stream>>>(outh, eW, eb, em);
  k6_crf<<<32, 64, 0, stream>>>(sentence, tags, em, trans, startv, endv, (float*)d_out);
}

// Round 5
// 1650.041 us; speedup vs baseline: 1.0243x; 1.0243x over previous
//
#include <hip/hip_runtime.h>
#include <math.h>

#define SS 128
#define BB 32
#define CC 16
#define DW 256
#define DC 64
#define HC 128
#define KX 384   // DW + HC
#define TT 17

typedef __attribute__((ext_vector_type(8))) short bf16x8;
typedef __attribute__((ext_vector_type(4))) float f32x4;
typedef unsigned long long ull_t;

__device__ __forceinline__ float sigf(float x) { return 1.0f / (1.0f + __expf(-x)); }
__device__ __forceinline__ float tanhfast(float x) {
  float xc = fminf(fmaxf(x, -15.f), 15.f);
  float e = __expf(2.f * xc);
  return (e - 1.f) / (e + 1.f);
}
__device__ __forceinline__ unsigned short f2bf(float x) {
  unsigned int u = __float_as_uint(x);
  u += 0x7FFF + ((u >> 16) & 1);
  return (unsigned short)(u >> 16);
}

// ---------------------------------------------------------------- K0: char ih vocab table
__global__ __launch_bounds__(256) void k0_ihvocab(
    const float* __restrict__ Wce,
    const float* __restrict__ WihF, const float* __restrict__ bF,
    const float* __restrict__ WihB, const float* __restrict__ bB,
    float* __restrict__ ihv) {
  int blk = blockIdx.x;          // 0..199
  int d = blk / 100, v = blk % 100;
  const float* Wih = d ? WihB : WihF;
  const float* bb  = d ? bB   : bF;
  __shared__ float ce[DC];
  if (threadIdx.x < DC) ce[threadIdx.x] = Wce[v * DC + threadIdx.x];
  __syncthreads();
  int g = threadIdx.x;
  float acc = bb[g];
  #pragma unroll 16
  for (int k = 0; k < DC; ++k) acc += ce[k] * Wih[g * DC + k];
  ihv[(d * 100 + v) * 256 + g] = acc;
}

// ---------------------------------------------------------------- K1: char BiLSTM (per-chain, no global sync)
__global__ __launch_bounds__(256) void k1_char(
    const int* __restrict__ charidx,   // (B,S,C)
    const float* __restrict__ WhhF, const float* __restrict__ WhhB,
    const float* __restrict__ ihv,     // (2,100,256)
    float* __restrict__ x)             // (4096, 384)
{
  int blk = blockIdx.x;
  int d = blk >> 8;
  int n0 = (blk & 255) * 16;
  const float* Whh = d ? WhhB : WhhF;

  __shared__ float Wl[256 * 68];
  __shared__ float hl[16 * 68];

  for (int i = threadIdx.x; i < 256 * 64; i += 256) {
    int g = i >> 6, k = i & 63;
    Wl[g * 68 + k] = Whh[i];
  }
  __syncthreads();

  int hh = threadIdx.x & 63;
  int ng = threadIdx.x >> 6;
  float c[4] = {0.f, 0.f, 0.f, 0.f};
  float h[4] = {0.f, 0.f, 0.f, 0.f};
  int bb_[4], ss_[4];
  #pragma unroll
  for (int m = 0; m < 4; ++m) {
    int n = n0 + ng + 4 * m;
    bb_[m] = n >> 7; ss_[m] = n & 127;
  }

  for (int t = 0; t < CC; ++t) {
    int cpos = d ? (CC - 1 - t) : t;
    float acc[4][4];
    #pragma unroll
    for (int m = 0; m < 4; ++m) {
      int v = charidx[bb_[m] * (SS * CC) + ss_[m] * CC + cpos];
      const float* base = ihv + (d * 100 + v) * 256 + hh;
      acc[m][0] = base[0]; acc[m][1] = base[64]; acc[m][2] = base[128]; acc[m][3] = base[192];
    }
    if (t > 0) {
      #pragma unroll 4
      for (int k = 0; k < 64; k += 4) {
        float4 w4[4];
        #pragma unroll
        for (int q = 0; q < 4; ++q)
          w4[q] = *(const float4*)&Wl[(q * 64 + hh) * 68 + k];
        #pragma unroll
        for (int m = 0; m < 4; ++m) {
          float4 h4 = *(const float4*)&hl[(ng + 4 * m) * 68 + k];
          #pragma unroll
          for (int q = 0; q < 4; ++q)
            acc[m][q] += h4.x * w4[q].x + h4.y * w4[q].y + h4.z * w4[q].z + h4.w * w4[q].w;
        }
      }
      __syncthreads();
    }
    #pragma unroll
    for (int m = 0; m < 4; ++m) {
      float ig = sigf(acc[m][0]);
      float fg = sigf(acc[m][1]);
      float gg = tanhfast(acc[m][2]);
      float og = sigf(acc[m][3]);
      c[m] = fg * c[m] + ig * gg;
      h[m] = og * tanhfast(c[m]);
      hl[(ng + 4 * m) * 68 + hh] = h[m];
    }
    __syncthreads();
  }
  #pragma unroll
  for (int m = 0; m < 4; ++m) {
    int row = ss_[m] * BB + bb_[m];
    x[row * KX + d * 64 + hh] = h[m];
  }
}

// ---------------------------------------------------------------- K2: word embedding gather
__global__ __launch_bounds__(64) void k2_we(
    const int* __restrict__ sentence, const float* __restrict__ Wwe,
    float* __restrict__ x) {
  int row = blockIdx.x;
  int idx = sentence[row];
  const float4* src = (const float4*)(Wwe + (size_t)idx * DW);
  float4* dst = (float4*)(x + (size_t)row * KX + HC);
  dst[threadIdx.x] = src[threadIdx.x];
}

// ---------------------------------------------------------------- K3: word ih GEMM  wg[d][row][g]
__global__ __launch_bounds__(256) void k3_ihgemm(
    const float* __restrict__ x,
    const float* __restrict__ WihF, const float* __restrict__ bF,
    const float* __restrict__ WihB, const float* __restrict__ bB,
    float* __restrict__ wg) {
  int n0 = blockIdx.x * 128;
  int m0 = blockIdx.y * 128;
  int d  = n0 >> 10;
  int gb = n0 & 1023;
  const float* Wih  = d ? WihB : WihF;
  const float* bias = d ? bB   : bF;

  __shared__ float At[32][132];
  __shared__ float Bt[32][132];

  int tid = threadIdx.x;
  int half = tid & 1, r = tid >> 1;
  int tm = tid & 15, tn = tid >> 4;
  float acc[8][8] = {};

  for (int k0 = 0; k0 < KX; k0 += 32) {
    __syncthreads();
    {
      const float4* srcA = (const float4*)(x + (size_t)(m0 + r) * KX + k0 + half * 16);
      const float4* srcB = (const float4*)(Wih + (size_t)(gb + r) * KX + k0 + half * 16);
      #pragma unroll
      for (int q = 0; q < 4; ++q) {
        float4 v = srcA[q];
        int kk = half * 16 + q * 4;
        At[kk + 0][r] = v.x; At[kk + 1][r] = v.y; At[kk + 2][r] = v.z; At[kk + 3][r] = v.w;
      }
      #pragma unroll
      for (int q = 0; q < 4; ++q) {
        float4 v = srcB[q];
        int kk = half * 16 + q * 4;
        Bt[kk + 0][r] = v.x; Bt[kk + 1][r] = v.y; Bt[kk + 2][r] = v.z; Bt[kk + 3][r] = v.w;
      }
    }
    __syncthreads();
    #pragma unroll 8
    for (int k = 0; k < 32; ++k) {
      float4 a0 = *(const float4*)&At[k][tm * 8];
      float4 a1 = *(const float4*)&At[k][tm * 8 + 4];
      float4 b0 = *(const float4*)&Bt[k][tn * 8];
      float4 b1 = *(const float4*)&Bt[k][tn * 8 + 4];
      float av[8] = {a0.x, a0.y, a0.z, a0.w, a1.x, a1.y, a1.z, a1.w};
      float bv[8] = {b0.x, b0.y, b0.z, b0.w, b1.x, b1.y, b1.z, b1.w};
      #pragma unroll
      for (int i = 0; i < 8; ++i)
        #pragma unroll
        for (int jq = 0; jq < 8; ++jq)
          acc[i][jq] += av[i] * bv[jq];
    }
  }
  float bv8[8];
  #pragma unroll
  for (int jq = 0; jq < 8; ++jq) bv8[jq] = bias[gb + tn * 8 + jq];
  #pragma unroll
  for (int i = 0; i < 8; ++i) {
    int m = m0 + tm * 8 + i;
    float* dst = wg + ((size_t)(d * 4096 + m)) * 1024 + gb + tn * 8;
    float4 v0 = {acc[i][0] + bv8[0], acc[i][1] + bv8[1], acc[i][2] + bv8[2], acc[i][3] + bv8[3]};
    float4 v1 = {acc[i][4] + bv8[4], acc[i][5] + bv8[5], acc[i][6] + bv8[6], acc[i][7] + bv8[7]};
    *(float4*)dst = v0; *(float4*)(dst + 4) = v1;
  }
}

// ---------------------------------------------------------------- K3b: pack streamed Whh quarter (ch=1, ks=4..7) as bf16 frags
// Layout: wstr[((d*8 + w)*16 + q*4 + (ks-4)) * 512 + lane*8] (shorts).
__global__ __launch_bounds__(64) void k3b_pack(
    const float* __restrict__ WhhF, const float* __restrict__ WhhB,
    unsigned short* __restrict__ wstr) {
  int bid = blockIdx.x;            // 0..255
  int d = bid >> 7;
  int rem = bid & 127;             // w*16 + fidx
  int w = rem >> 4, fidx = rem & 15;
  int q = fidx >> 2, ks = (fidx & 3) + 4;
  const float* Whh = d ? WhhB : WhhF;
  int l = threadIdx.x, l15 = l & 15, q4 = l >> 4;
  const float* wr = Whh + (size_t)(q * 256 + w * 32 + 16 + l15) * 256 + ks * 32 + q4 * 8;
  float4 lo = *(const float4*)(wr);
  float4 hi = *(const float4*)(wr + 4);
  bf16x8 f;
  f[0] = (short)f2bf(lo.x); f[1] = (short)f2bf(lo.y);
  f[2] = (short)f2bf(lo.z); f[3] = (short)f2bf(lo.w);
  f[4] = (short)f2bf(hi.x); f[5] = (short)f2bf(hi.y);
  f[6] = (short)f2bf(hi.z); f[7] = (short)f2bf(hi.w);
  *(bf16x8*)(wstr + (size_t)(bid * 512 + l * 8)) = f;
}

// ---------------------------------------------------------------- K4: word BiLSTM recurrence (batch-split, barrier-synced)
// 4 WGs = 2 dir x 2 batch-halves; each WG: 8 waves x 512 thr, owns 16 batches
// and ALL 256 h-cols. Wave w owns cols j0=w*32..+31 x 4 gates (N=128, M=16,
// K=256 -> 64 MFMA 16x16x32 per wave per step). h exchange: LDS + 1 barrier
// per step. Whh per wave (64KB bf16): 32 frags resident VGPR (ch=0), 16 in
// LDS (ch=1 ks0..3), 16 streamed from L2 each step (ch=1 ks4..7, prepacked).
//
// VGPR budget: rounds 2-4 all compiled at a 128-VGPR cap (launch_bounds'
// 2nd arg behaves CUDA-style min-BLOCKS here: (512,2)->4 waves/EU->128;
// bare (512) default also 128; waves_per_eu + launch_bounds ignored).
// This round: NO launch_bounds at all; backend-native attribute pair
// flat_work_group_size(512,512) + waves_per_eu(2,2) -> cap 512/2 = 256.
// Verification signal: VGPR_Count ~= 240-256.
//
// Barrier: raw lgkmcnt(0)-only s_barrier (NOT __syncthreads, which drains
// vmcnt(0) and serializes the stream/gate-prefetch global loads every step).
// LDS correctness needs only ds-op completion (lgkmcnt) before the barrier;
// global loads stay in flight across it (T4 counted-wait pattern).
__global__
__attribute__((amdgpu_flat_work_group_size(512, 512)))
__attribute__((amdgpu_waves_per_eu(2, 2)))
void k4_word(
    const float* __restrict__ WhhF, const float* __restrict__ WhhB,
    const float* __restrict__ wg,           // (2,4096,1024) f32
    float* __restrict__ outh,               // (4096,512) f32
    const unsigned short* __restrict__ wstr) {
  const int blk = blockIdx.x;               // 0..3
  const int d = blk >> 1, half = blk & 1;
  const int tid = threadIdx.x;
  const int w = tid >> 6;                   // wave 0..7
  const int l = tid & 63;
  const int l15 = l & 15, q4 = l >> 4;
  const int j0 = w * 32;
  const float* __restrict__ Whh = d ? WhhB : WhhF;

  __shared__ unsigned short ldsw[8 * 16 * 64 * 8];   // 131072 B: weight frags
  __shared__ unsigned short hsh[2 * 16 * 256];       // 16384 B: h double-buffer (swizzled)

  // ---- resident Bf: ch=0 (cols j0..j0+15), q=0..3, ks=0..7
  bf16x8 Bf[4][8];
  #pragma unroll
  for (int q = 0; q < 4; ++q) {
    const float* wr = Whh + (size_t)(q * 256 + j0 + l15) * 256 + q4 * 8;
    #pragma unroll
    for (int ks = 0; ks < 8; ++ks) {
      float4 lo = *(const float4*)(wr + ks * 32);
      float4 hi = *(const float4*)(wr + ks * 32 + 4);
      bf16x8 f;
      f[0] = (short)f2bf(lo.x); f[1] = (short)f2bf(lo.y);
      f[2] = (short)f2bf(lo.z); f[3] = (short)f2bf(lo.w);
      f[4] = (short)f2bf(hi.x); f[5] = (short)f2bf(hi.y);
      f[6] = (short)f2bf(hi.z); f[7] = (short)f2bf(hi.w);
      Bf[q][ks] = f;
    }
  }
  // ---- LDS weights: ch=1 (cols j0+16..j0+31), ks=0..3 (one-time, wave-own)
  #pragma unroll
  for (int q = 0; q < 4; ++q) {
    const float* wr = Whh + (size_t)(q * 256 + j0 + 16 + l15) * 256 + q4 * 8;
    #pragma unroll
    for (int ks = 0; ks < 4; ++ks) {
      float4 lo = *(const float4*)(wr + ks * 32);
      float4 hi = *(const float4*)(wr + ks * 32 + 4);
      bf16x8 f;
      f[0] = (short)f2bf(lo.x); f[1] = (short)f2bf(lo.y);
      f[2] = (short)f2bf(lo.z); f[3] = (short)f2bf(lo.w);
      f[4] = (short)f2bf(hi.x); f[5] = (short)f2bf(hi.y);
      f[6] = (short)f2bf(hi.z); f[7] = (short)f2bf(hi.w);
      *(bf16x8*)&ldsw[((w * 16 + q * 4 + ks) * 64 + l) * 8] = f;
    }
  }

  const unsigned short* sbase = wstr + (size_t)(d * 8 + w) * 8192;  // 16 frags * 512 shorts

  f32x4 acc[4][2];
  float cst[8];
  #pragma unroll
  for (int i = 0; i < 8; ++i) cst[i] = 0.f;

  // ---- prologue: gates for t=0
  {
    const int s0 = d ? (SS - 1) : 0;
    const float* wgs = wg + ((size_t)d * 4096 + (size_t)s0 * 32 + half * 16) * 1024 + j0 + l15;
    #pragma unroll
    for (int q = 0; q < 4; ++q)
      #pragma unroll
      for (int ch = 0; ch < 2; ++ch)
        #pragma unroll
        for (int r = 0; r < 4; ++r)
          acc[q][ch][r] = wgs[(size_t)(q4 * 4 + r) * 1024 + q * 256 + ch * 16];
  }

  bf16x8 Sb[8];
  for (int t = 0; t < SS; ++t) {
    const int s = d ? (SS - 1 - t) : t;

    if (t > 0) {
      // ---- issue stream chunk A (q=0,1 | ch1 | ks4..7) pre-barrier
      #pragma unroll
      for (int i = 0; i < 8; ++i)
        Sb[i] = *(const bf16x8*)(sbase + i * 512 + l * 8);
      // ---- lgkm-only barrier: ds publishes drained; global loads in flight
      __builtin_amdgcn_sched_barrier(0);
      asm volatile("s_waitcnt lgkmcnt(0)" ::: "memory");
      __builtin_amdgcn_s_barrier();
      __builtin_amdgcn_sched_barrier(0);
      const int pr = ((t - 1) & 1) * 4096;
      // ---- Af ks0..3 + issue stream chunk B early (covers khalf0 + q0,q1)
      bf16x8 Af0[4];
      #pragma unroll
      for (int ks = 0; ks < 4; ++ks)
        Af0[ks] = *(const bf16x8*)&hsh[pr + l15 * 256 + (((ks * 4 + q4) ^ (l15 & 7)) * 8)];
      bf16x8 Sb2[8];
      #pragma unroll
      for (int i = 0; i < 8; ++i)
        Sb2[i] = *(const bf16x8*)(sbase + (8 + i) * 512 + l * 8);
      // ---- khalf0: Af ks0..3, resident + LDS weights
      #pragma unroll
      for (int q = 0; q < 4; ++q) {
        #pragma unroll
        for (int ks = 0; ks < 4; ++ks)
          acc[q][0] = __builtin_amdgcn_mfma_f32_16x16x32_bf16(Af0[ks], Bf[q][ks], acc[q][0], 0, 0, 0);
        #pragma unroll
        for (int ks = 0; ks < 4; ++ks) {
          bf16x8 bw = *(const bf16x8*)&ldsw[((w * 16 + q * 4 + ks) * 64 + l) * 8];
          acc[q][1] = __builtin_amdgcn_mfma_f32_16x16x32_bf16(Af0[ks], bw, acc[q][1], 0, 0, 0);
        }
      }
      // ---- khalf1: Af ks4..7, resident + streamed
      bf16x8 Af1[4];
      #pragma unroll
      for (int ks = 0; ks < 4; ++ks)
        Af1[ks] = *(const bf16x8*)&hsh[pr + l15 * 256 + ((((ks + 4) * 4 + q4) ^ (l15 & 7)) * 8)];
      #pragma unroll
      for (int q = 0; q < 4; ++q)
        #pragma unroll
        for (int ks = 0; ks < 4; ++ks)
          acc[q][0] = __builtin_amdgcn_mfma_f32_16x16x32_bf16(Af1[ks], Bf[q][ks + 4], acc[q][0], 0, 0, 0);
      #pragma unroll
      for (int q = 0; q < 2; ++q)
        #pragma unroll
        for (int kk = 0; kk < 4; ++kk)
          acc[q][1] = __builtin_amdgcn_mfma_f32_16x16x32_bf16(Af1[kk], Sb[q * 4 + kk], acc[q][1], 0, 0, 0);
      #pragma unroll
      for (int q = 2; q < 4; ++q)
        #pragma unroll
        for (int kk = 0; kk < 4; ++kk)
          acc[q][1] = __builtin_amdgcn_mfma_f32_16x16x32_bf16(Af1[kk], Sb2[(q - 2) * 4 + kk], acc[q][1], 0, 0, 0);
    }

    // ---- activations; lane owns (b = half*16 + q4*4+r, col = j0 + ch*16 + l15)
    float hv[8];
    #pragma unroll
    for (int ch = 0; ch < 2; ++ch)
      #pragma unroll
      for (int r = 0; r < 4; ++r) {
        int ix = ch * 4 + r;
        float ig = sigf(acc[0][ch][r]);
        float fg = sigf(acc[1][ch][r]);
        float gg = tanhfast(acc[2][ch][r]);
        float og = sigf(acc[3][ch][r]);
        float c2 = fg * cst[ix] + ig * gg;
        cst[ix] = c2;
        hv[ix] = og * tanhfast(c2);
      }

    // ---- gates for t+1 (issued early; latency hides under next barrier+MFMA)
    if (t < SS - 1) {
      const int sn = d ? (SS - 2 - t) : (t + 1);
      const float* wgs = wg + ((size_t)d * 4096 + (size_t)sn * 32 + half * 16) * 1024 + j0 + l15;
      #pragma unroll
      for (int q = 0; q < 4; ++q)
        #pragma unroll
        for (int ch = 0; ch < 2; ++ch)
          #pragma unroll
          for (int r = 0; r < 4; ++r)
            acc[q][ch][r] = wgs[(size_t)(q4 * 4 + r) * 1024 + q * 256 + ch * 16];
    }

    // ---- publish h_t to LDS (swizzled: 16B-unit ^= row&7)
    {
      const int p = (t & 1) * 4096;
      #pragma unroll
      for (int ch = 0; ch < 2; ++ch)
        #pragma unroll
        for (int r = 0; r < 4; ++r) {
          int b = q4 * 4 + r;
          int col = j0 + ch * 16 + l15;
          hsh[p + b * 256 + (((col >> 3) ^ (b & 7)) * 8) + (col & 7)] = f2bf(hv[ch * 4 + r]);
        }
    }

    // ---- outh (non-temporal, off critical path)
    {
      float* op = outh + ((size_t)(s * 32 + half * 16)) * 512 + d * 256 + j0 + l15;
      #pragma unroll
      for (int ch = 0; ch < 2; ++ch)
        #pragma unroll
        for (int r = 0; r < 4; ++r)
          __builtin_nontemporal_store(hv[ch * 4 + r], op + (size_t)(q4 * 4 + r) * 512 + ch * 16);
    }
  }
}

// ---------------------------------------------------------------- K5: emit GEMM (tiny)
__global__ __launch_bounds__(64) void k5_emit(
    const float* __restrict__ outh, const float* __restrict__ eW,
    const float* __restrict__ eb, float* __restrict__ em) {
  int row = blockIdx.x;
  int t = threadIdx.x;
  if (t < TT) {
    const float4* o4 = (const float4*)(outh + (size_t)row * 512);
    const float4* w4 = (const float4*)(eW + (size_t)t * 512);
    float acc = 0.f;
    #pragma unroll 16
    for (int k = 0; k < 128; ++k) {
      float4 a = o4[k], bq = w4[k];
      acc += a.x * bq.x + a.y * bq.y + a.z * bq.z + a.w * bq.w;
    }
    em[row * TT + t] = acc + eb[t];
  }
}

// ---------------------------------------------------------------- K6: CRF NLL (32 independent batches)
__global__ __launch_bounds__(64) void k6_crf(
    const int* __restrict__ sentence, const int* __restrict__ tags,
    const float* __restrict__ em, const float* __restrict__ trans,
    const float* __restrict__ startv, const float* __restrict__ endv,
    float* __restrict__ outp) {
  int b = blockIdx.x;
  int j = threadIdx.x;
  __shared__ float ash[TT];
  __shared__ float red[TT];
  float tc[TT];
  float alpha = 0.f;
  if (j < TT) {
    #pragma unroll
    for (int i = 0; i < TT; ++i) tc[i] = trans[i * TT + j];
    alpha = startv[j] + em[(0 * BB + b) * TT + j];
  }
  for (int s = 1; s < SS; ++s) {
    if (j < TT) ash[j] = alpha;
    __syncthreads();
    int m = (sentence[s * BB + b] != 1) ? 1 : 0;
    if (j < TT) {
      float mx = -1e30f;
      #pragma unroll
      for (int i = 0; i < TT; ++i) mx = fmaxf(mx, ash[i] + tc[i]);
      float sum = 0.f;
      #pragma unroll
      for (int i = 0; i < TT; ++i) sum += __expf(ash[i] + tc[i] - mx);
      float nxt = mx + __logf(sum) + em[(s * BB + b) * TT + j];
      if (m) alpha = nxt;
    }
    __syncthreads();
  }
  if (j < TT) red[j] = alpha + endv[j];
  __syncthreads();
  if (j == 0) {
    float mx = -1e30f;
    for (int i = 0; i < TT; ++i) mx = fmaxf(mx, red[i]);
    float sum = 0.f;
    for (int i = 0; i < TT; ++i) sum += __expf(red[i] - mx);
    float den = mx + __logf(sum);
    int prev = tags[0 * BB + b];
    float num = startv[prev] + em[(0 * BB + b) * TT + prev];
    for (int s = 1; s < SS; ++s) {
      int tg = tags[s * BB + b];
      if (sentence[s * BB + b] != 1) {
        num += trans[prev * TT + tg] + em[(s * BB + b) * TT + tg];
        prev = tg;
      }
    }
    num += endv[prev];
    atomicAdd(outp, den - num);
  }
}

// ---------------------------------------------------------------- launcher
extern "C" void kernel_launch(void* const* d_in, const int* in_sizes, int n_in,
                              void* d_out, int out_size, void* d_ws, size_t ws_size,
                              hipStream_t stream) {
  (void)in_sizes; (void)n_in; (void)out_size; (void)ws_size;
  const int*   sentence = (const int*)d_in[0];
  const int*   charidx  = (const int*)d_in[1];
  const int*   tags     = (const int*)d_in[2];
  const float* Wwe   = (const float*)d_in[3];
  const float* Wce   = (const float*)d_in[4];
  const float* cWihF = (const float*)d_in[5];
  const float* cWhhF = (const float*)d_in[6];
  const float* cbF   = (const float*)d_in[7];
  const float* wWihF = (const float*)d_in[8];
  const float* wWhhF = (const float*)d_in[9];
  const float* wbF   = (const float*)d_in[10];
  const float* cWihB = (const float*)d_in[11];
  const float* cWhhB = (const float*)d_in[12];
  const float* cbB   = (const float*)d_in[13];
  const float* wWihB = (const float*)d_in[14];
  const float* wWhhB = (const float*)d_in[15];
  const float* wbB   = (const float*)d_in[16];
  const float* eW    = (const float*)d_in[17];
  const float* eb    = (const float*)d_in[18];
  const float* trans = (const float*)d_in[19];
  const float* startv= (const float*)d_in[20];
  const float* endv  = (const float*)d_in[21];

  char* ws = (char*)d_ws;
  float*          ihv   = (float*)(ws + 512);             //  204800 B
  float*          x     = (float*)(ws + 205312);          // 6291456 B
  float*          wg    = (float*)(ws + 6496768);         // 33554432 B
  float*          outh  = (float*)(ws + 40116736);        // 8388608 B
  float*          em    = (float*)(ws + 48505344);        //  278528 B
  // wstr (262144 B) aliases the head of the em region: em is written only by
  // k5 (after k4 completes), so the packed stream-weight buffer is dead by then.
  unsigned short* wstr  = (unsigned short*)(ws + 48505344);
  // total ws usage: 48,783,872 B (unchanged)

  hipMemsetAsync(d_out, 0, sizeof(float), stream);

  k3b_pack<<<256, 64, 0, stream>>>(wWhhF, wWhhB, wstr);
  k0_ihvocab<<<200, 256, 0, stream>>>(Wce, cWihF, cbF, cWihB, cbB, ihv);
  k1_char<<<512, 256, 0, stream>>>(charidx, cWhhF, cWhhB, ihv, x);
  k2_we<<<4096, 64, 0, stream>>>(sentence, Wwe, x);
  k3_ihgemm<<<dim3(16, 32), 256, 0, stream>>>(x, wWihF, wbF, wWihB, wbB, wg);
  k4_word<<<4, 512, 0, stream>>>(wWhhF, wWhhB, wg, outh, wstr);
  k5_emit<<<4096, 64, 0, stream>>>(outh, eW, eb, em);
  k6_crf<<<32, 64, 0, stream>>>(sentence, tags, em, trans, startv, endv, (float*)d_out);
}

// Round 6
// 1384.546 us; speedup vs baseline: 1.2207x; 1.1918x over previous
//
#include <hip/hip_runtime.h>
#include <math.h>

#define SS 128
#define BB 32
#define CC 16
#define DW 256
#define DC 64
#define HC 128
#define KX 384   // DW + HC
#define TT 17

typedef __attribute__((ext_vector_type(8))) short bf16x8;
typedef __attribute__((ext_vector_type(4))) float f32x4;
typedef unsigned long long ull_t;

__device__ __forceinline__ float sigf(float x) { return 1.0f / (1.0f + __expf(-x)); }
__device__ __forceinline__ float tanhfast(float x) {
  float xc = fminf(fmaxf(x, -15.f), 15.f);
  float e = __expf(2.f * xc);
  return (e - 1.f) / (e + 1.f);
}
__device__ __forceinline__ unsigned short f2bf(float x) {
  unsigned int u = __float_as_uint(x);
  u += 0x7FFF + ((u >> 16) & 1);
  return (unsigned short)(u >> 16);
}

// ---------------------------------------------------------------- K0: char ih vocab table
__global__ __launch_bounds__(256) void k0_ihvocab(
    const float* __restrict__ Wce,
    const float* __restrict__ WihF, const float* __restrict__ bF,
    const float* __restrict__ WihB, const float* __restrict__ bB,
    float* __restrict__ ihv) {
  int blk = blockIdx.x;          // 0..199
  int d = blk / 100, v = blk % 100;
  const float* Wih = d ? WihB : WihF;
  const float* bb  = d ? bB   : bF;
  __shared__ float ce[DC];
  if (threadIdx.x < DC) ce[threadIdx.x] = Wce[v * DC + threadIdx.x];
  __syncthreads();
  int g = threadIdx.x;
  float acc = bb[g];
  #pragma unroll 16
  for (int k = 0; k < DC; ++k) acc += ce[k] * Wih[g * DC + k];
  ihv[(d * 100 + v) * 256 + g] = acc;
}

// ---------------------------------------------------------------- K1: char BiLSTM (per-chain, no global sync)
__global__ __launch_bounds__(256) void k1_char(
    const int* __restrict__ charidx,   // (B,S,C)
    const float* __restrict__ WhhF, const float* __restrict__ WhhB,
    const float* __restrict__ ihv,     // (2,100,256)
    float* __restrict__ x)             // (4096, 384)
{
  int blk = blockIdx.x;
  int d = blk >> 8;
  int n0 = (blk & 255) * 16;
  const float* Whh = d ? WhhB : WhhF;

  __shared__ float Wl[256 * 68];
  __shared__ float hl[16 * 68];

  for (int i = threadIdx.x; i < 256 * 64; i += 256) {
    int g = i >> 6, k = i & 63;
    Wl[g * 68 + k] = Whh[i];
  }
  __syncthreads();

  int hh = threadIdx.x & 63;
  int ng = threadIdx.x >> 6;
  float c[4] = {0.f, 0.f, 0.f, 0.f};
  float h[4] = {0.f, 0.f, 0.f, 0.f};
  int bb_[4], ss_[4];
  #pragma unroll
  for (int m = 0; m < 4; ++m) {
    int n = n0 + ng + 4 * m;
    bb_[m] = n >> 7; ss_[m] = n & 127;
  }

  for (int t = 0; t < CC; ++t) {
    int cpos = d ? (CC - 1 - t) : t;
    float acc[4][4];
    #pragma unroll
    for (int m = 0; m < 4; ++m) {
      int v = charidx[bb_[m] * (SS * CC) + ss_[m] * CC + cpos];
      const float* base = ihv + (d * 100 + v) * 256 + hh;
      acc[m][0] = base[0]; acc[m][1] = base[64]; acc[m][2] = base[128]; acc[m][3] = base[192];
    }
    if (t > 0) {
      #pragma unroll 4
      for (int k = 0; k < 64; k += 4) {
        float4 w4[4];
        #pragma unroll
        for (int q = 0; q < 4; ++q)
          w4[q] = *(const float4*)&Wl[(q * 64 + hh) * 68 + k];
        #pragma unroll
        for (int m = 0; m < 4; ++m) {
          float4 h4 = *(const float4*)&hl[(ng + 4 * m) * 68 + k];
          #pragma unroll
          for (int q = 0; q < 4; ++q)
            acc[m][q] += h4.x * w4[q].x + h4.y * w4[q].y + h4.z * w4[q].z + h4.w * w4[q].w;
        }
      }
      __syncthreads();
    }
    #pragma unroll
    for (int m = 0; m < 4; ++m) {
      float ig = sigf(acc[m][0]);
      float fg = sigf(acc[m][1]);
      float gg = tanhfast(acc[m][2]);
      float og = sigf(acc[m][3]);
      c[m] = fg * c[m] + ig * gg;
      h[m] = og * tanhfast(c[m]);
      hl[(ng + 4 * m) * 68 + hh] = h[m];
    }
    __syncthreads();
  }
  #pragma unroll
  for (int m = 0; m < 4; ++m) {
    int row = ss_[m] * BB + bb_[m];
    x[row * KX + d * 64 + hh] = h[m];
  }
}

// ---------------------------------------------------------------- K2: word embedding gather
__global__ __launch_bounds__(64) void k2_we(
    const int* __restrict__ sentence, const float* __restrict__ Wwe,
    float* __restrict__ x) {
  int row = blockIdx.x;
  int idx = sentence[row];
  const float4* src = (const float4*)(Wwe + (size_t)idx * DW);
  float4* dst = (float4*)(x + (size_t)row * KX + HC);
  dst[threadIdx.x] = src[threadIdx.x];
}

// ---------------------------------------------------------------- K3: word ih GEMM  wg[d][row][g]
__global__ __launch_bounds__(256) void k3_ihgemm(
    const float* __restrict__ x,
    const float* __restrict__ WihF, const float* __restrict__ bF,
    const float* __restrict__ WihB, const float* __restrict__ bB,
    float* __restrict__ wg) {
  int n0 = blockIdx.x * 128;
  int m0 = blockIdx.y * 128;
  int d  = n0 >> 10;
  int gb = n0 & 1023;
  const float* Wih  = d ? WihB : WihF;
  const float* bias = d ? bB   : bF;

  __shared__ float At[32][132];
  __shared__ float Bt[32][132];

  int tid = threadIdx.x;
  int half = tid & 1, r = tid >> 1;
  int tm = tid & 15, tn = tid >> 4;
  float acc[8][8] = {};

  for (int k0 = 0; k0 < KX; k0 += 32) {
    __syncthreads();
    {
      const float4* srcA = (const float4*)(x + (size_t)(m0 + r) * KX + k0 + half * 16);
      const float4* srcB = (const float4*)(Wih + (size_t)(gb + r) * KX + k0 + half * 16);
      #pragma unroll
      for (int q = 0; q < 4; ++q) {
        float4 v = srcA[q];
        int kk = half * 16 + q * 4;
        At[kk + 0][r] = v.x; At[kk + 1][r] = v.y; At[kk + 2][r] = v.z; At[kk + 3][r] = v.w;
      }
      #pragma unroll
      for (int q = 0; q < 4; ++q) {
        float4 v = srcB[q];
        int kk = half * 16 + q * 4;
        Bt[kk + 0][r] = v.x; Bt[kk + 1][r] = v.y; Bt[kk + 2][r] = v.z; Bt[kk + 3][r] = v.w;
      }
    }
    __syncthreads();
    #pragma unroll 8
    for (int k = 0; k < 32; ++k) {
      float4 a0 = *(const float4*)&At[k][tm * 8];
      float4 a1 = *(const float4*)&At[k][tm * 8 + 4];
      float4 b0 = *(const float4*)&Bt[k][tn * 8];
      float4 b1 = *(const float4*)&Bt[k][tn * 8 + 4];
      float av[8] = {a0.x, a0.y, a0.z, a0.w, a1.x, a1.y, a1.z, a1.w};
      float bv[8] = {b0.x, b0.y, b0.z, b0.w, b1.x, b1.y, b1.z, b1.w};
      #pragma unroll
      for (int i = 0; i < 8; ++i)
        #pragma unroll
        for (int jq = 0; jq < 8; ++jq)
          acc[i][jq] += av[i] * bv[jq];
    }
  }
  float bv8[8];
  #pragma unroll
  for (int jq = 0; jq < 8; ++jq) bv8[jq] = bias[gb + tn * 8 + jq];
  #pragma unroll
  for (int i = 0; i < 8; ++i) {
    int m = m0 + tm * 8 + i;
    float* dst = wg + ((size_t)(d * 4096 + m)) * 1024 + gb + tn * 8;
    float4 v0 = {acc[i][0] + bv8[0], acc[i][1] + bv8[1], acc[i][2] + bv8[2], acc[i][3] + bv8[3]};
    float4 v1 = {acc[i][4] + bv8[4], acc[i][5] + bv8[5], acc[i][6] + bv8[6], acc[i][7] + bv8[7]};
    *(float4*)dst = v0; *(float4*)(dst + 4) = v1;
  }
}

// ---------------------------------------------------------------- K3b: pack ALL streamed Whh frags (40 per (d,wave)) as bf16
// Stream order per (d,w):
//   fidx 0..7   : ch0, q=fidx>>1,        ks=2+(fidx&1)      (chunk S0)
//   fidx 8..23  : ch0, q=(fidx-8)>>2,    ks=4+((fidx-8)&3)  (chunks S1,S2)
//   fidx 24..39 : ch1, q=(fidx-24)>>2,   ks=4+((fidx-24)&3) (chunks S3,S4)
// wstr[((d*8+w)*40 + fidx)*512 + lane*8]
__global__ __launch_bounds__(64) void k3b_pack(
    const float* __restrict__ WhhF, const float* __restrict__ WhhB,
    unsigned short* __restrict__ wstr) {
  int bid = blockIdx.x;            // 0..639
  int fidx = bid % 40;
  int dw = bid / 40;               // 0..15
  int d = dw >> 3, w = dw & 7;
  int ch, q, ks;
  if (fidx < 8)       { ch = 0; q = fidx >> 1;        ks = 2 + (fidx & 1); }
  else if (fidx < 24) { ch = 0; q = (fidx - 8) >> 2;  ks = 4 + ((fidx - 8) & 3); }
  else                { ch = 1; q = (fidx - 24) >> 2; ks = 4 + ((fidx - 24) & 3); }
  const float* Whh = d ? WhhB : WhhF;
  int l = threadIdx.x, l15 = l & 15, q4 = l >> 4;
  const float* wr = Whh + (size_t)(q * 256 + w * 32 + ch * 16 + l15) * 256 + ks * 32 + q4 * 8;
  float4 lo = *(const float4*)(wr);
  float4 hi = *(const float4*)(wr + 4);
  bf16x8 f;
  f[0] = (short)f2bf(lo.x); f[1] = (short)f2bf(lo.y);
  f[2] = (short)f2bf(lo.z); f[3] = (short)f2bf(lo.w);
  f[4] = (short)f2bf(hi.x); f[5] = (short)f2bf(hi.y);
  f[6] = (short)f2bf(hi.z); f[7] = (short)f2bf(hi.w);
  *(bf16x8*)(wstr + (size_t)bid * 512 + l * 8) = f;
}

// ---------------------------------------------------------------- K4: word BiLSTM recurrence (batch-split, barrier-synced, L2-stream)
// 4 WGs = 2 dir x 2 batch-halves; 8 waves x 512 thr; wave owns cols
// j0=w*32..+31 x 4 gates (M=16, K=256 -> 64 MFMA/wave/step).
// DESIGNED FOR THE 128-VGPR CAP (toolchain pins 512-thr kernels at 128;
// rounds 2-5 proved no attribute moves it):
//   VGPR-resident:  ch0 ks0..1  ( 8 frags, 32 regs)
//   LDS-resident:   ch1 ks0..3  (16 frags/wave, 128KB/WG, loaded once)
//   L2-streamed:    ch0 ks2..7 + ch1 ks4..7 (40 frags/wave/step, prepacked
//                   by k3b, consumed in 5 chunks of 8 through ONE 32-reg
//                   buffer: MFMA chunk c, then load chunk c+1 -> no spill).
// Per-CU per-step stream = 320KB over ~64B/cy L1 port ~= 5120cy ~= 2.1us.
// h exchange: LDS double-buffer + lgkm-only barrier (global loads stay in
// flight across it). No atomics, no cross-WG traffic.
__global__
__attribute__((amdgpu_flat_work_group_size(512, 512)))
void k4_word(
    const float* __restrict__ WhhF, const float* __restrict__ WhhB,
    const float* __restrict__ wg,           // (2,4096,1024) f32
    float* __restrict__ outh,               // (4096,512) f32
    const unsigned short* __restrict__ wstr) {
  const int blk = blockIdx.x;               // 0..3
  const int d = blk >> 1, half = blk & 1;
  const int tid = threadIdx.x;
  const int w = tid >> 6;                   // wave 0..7
  const int l = tid & 63;
  const int l15 = l & 15, q4 = l >> 4;
  const int j0 = w * 32;
  const float* __restrict__ Whh = d ? WhhB : WhhF;

  __shared__ unsigned short ldsw[8 * 16 * 64 * 8];   // 131072 B: ch1 ks0..3 weight frags
  __shared__ unsigned short hsh[2 * 16 * 256];       // 16384 B: h double-buffer (swizzled)

  // ---- resident Bf: ch=0 (cols j0..j0+15), q=0..3, ks=0..1 ONLY (32 VGPRs)
  bf16x8 Bf[4][2];
  #pragma unroll
  for (int q = 0; q < 4; ++q) {
    const float* wr = Whh + (size_t)(q * 256 + j0 + l15) * 256 + q4 * 8;
    #pragma unroll
    for (int ks = 0; ks < 2; ++ks) {
      float4 lo = *(const float4*)(wr + ks * 32);
      float4 hi = *(const float4*)(wr + ks * 32 + 4);
      bf16x8 f;
      f[0] = (short)f2bf(lo.x); f[1] = (short)f2bf(lo.y);
      f[2] = (short)f2bf(lo.z); f[3] = (short)f2bf(lo.w);
      f[4] = (short)f2bf(hi.x); f[5] = (short)f2bf(hi.y);
      f[6] = (short)f2bf(hi.z); f[7] = (short)f2bf(hi.w);
      Bf[q][ks] = f;
    }
  }
  // ---- LDS weights: ch=1 (cols j0+16..j0+31), ks=0..3 (one-time, wave-own)
  #pragma unroll
  for (int q = 0; q < 4; ++q) {
    const float* wr = Whh + (size_t)(q * 256 + j0 + 16 + l15) * 256 + q4 * 8;
    #pragma unroll
    for (int ks = 0; ks < 4; ++ks) {
      float4 lo = *(const float4*)(wr + ks * 32);
      float4 hi = *(const float4*)(wr + ks * 32 + 4);
      bf16x8 f;
      f[0] = (short)f2bf(lo.x); f[1] = (short)f2bf(lo.y);
      f[2] = (short)f2bf(lo.z); f[3] = (short)f2bf(lo.w);
      f[4] = (short)f2bf(hi.x); f[5] = (short)f2bf(hi.y);
      f[6] = (short)f2bf(hi.z); f[7] = (short)f2bf(hi.w);
      *(bf16x8*)&ldsw[((w * 16 + q * 4 + ks) * 64 + l) * 8] = f;
    }
  }

  const unsigned short* sbase = wstr + (size_t)(d * 8 + w) * 20480;  // 40 frags * 512 shorts

  f32x4 acc[4][2];
  float cst[8];
  #pragma unroll
  for (int i = 0; i < 8; ++i) cst[i] = 0.f;

  // ---- prologue: gates for t=0
  {
    const int s0 = d ? (SS - 1) : 0;
    const float* wgs = wg + ((size_t)d * 4096 + (size_t)s0 * 32 + half * 16) * 1024 + j0 + l15;
    #pragma unroll
    for (int q = 0; q < 4; ++q)
      #pragma unroll
      for (int ch = 0; ch < 2; ++ch)
        #pragma unroll
        for (int r = 0; r < 4; ++r)
          acc[q][ch][r] = wgs[(size_t)(q4 * 4 + r) * 1024 + q * 256 + ch * 16];
  }

  for (int t = 0; t < SS; ++t) {
    const int s = d ? (SS - 1 - t) : t;

    if (t > 0) {
      // ---- chunk S0 (ch0 q0..3 ks2,3) issued pre-barrier (hides under barrier wait)
      bf16x8 S0[8];
      #pragma unroll
      for (int i = 0; i < 8; ++i)
        S0[i] = *(const bf16x8*)(sbase + (size_t)i * 512 + l * 8);
      // ---- lgkm-only barrier: ds publishes drained; global loads in flight
      __builtin_amdgcn_sched_barrier(0);
      asm volatile("s_waitcnt lgkmcnt(0)" ::: "memory");
      __builtin_amdgcn_s_barrier();
      __builtin_amdgcn_sched_barrier(0);
      const int pr = ((t - 1) & 1) * 4096;
      // ---- A-fragments
      bf16x8 Af0[4];
      #pragma unroll
      for (int ks = 0; ks < 4; ++ks)
        Af0[ks] = *(const bf16x8*)&hsh[pr + l15 * 256 + (((ks * 4 + q4) ^ (l15 & 7)) * 8)];
      // ---- ch0 ks0,1 (VGPR-resident)
      #pragma unroll
      for (int q = 0; q < 4; ++q) {
        acc[q][0] = __builtin_amdgcn_mfma_f32_16x16x32_bf16(Af0[0], Bf[q][0], acc[q][0], 0, 0, 0);
        acc[q][0] = __builtin_amdgcn_mfma_f32_16x16x32_bf16(Af0[1], Bf[q][1], acc[q][0], 0, 0, 0);
      }
      // ---- ch1 ks0..3 (LDS-resident)
      #pragma unroll
      for (int q = 0; q < 4; ++q)
        #pragma unroll
        for (int ks = 0; ks < 4; ++ks) {
          bf16x8 bw = *(const bf16x8*)&ldsw[((w * 16 + q * 4 + ks) * 64 + l) * 8];
          acc[q][1] = __builtin_amdgcn_mfma_f32_16x16x32_bf16(Af0[ks], bw, acc[q][1], 0, 0, 0);
        }
      // ---- ch0 ks2,3 (stream chunk S0)
      #pragma unroll
      for (int q = 0; q < 4; ++q) {
        acc[q][0] = __builtin_amdgcn_mfma_f32_16x16x32_bf16(Af0[2], S0[q * 2 + 0], acc[q][0], 0, 0, 0);
        acc[q][0] = __builtin_amdgcn_mfma_f32_16x16x32_bf16(Af0[3], S0[q * 2 + 1], acc[q][0], 0, 0, 0);
      }
      bf16x8 Af1[4];
      #pragma unroll
      for (int ks = 0; ks < 4; ++ks)
        Af1[ks] = *(const bf16x8*)&hsh[pr + l15 * 256 + ((((ks + 4) * 4 + q4) ^ (l15 & 7)) * 8)];
      // ---- chunk S1: ch0 q0,1 ks4..7
      {
        bf16x8 S[8];
        #pragma unroll
        for (int i = 0; i < 8; ++i)
          S[i] = *(const bf16x8*)(sbase + (size_t)(8 + i) * 512 + l * 8);
        #pragma unroll
        for (int q = 0; q < 2; ++q)
          #pragma unroll
          for (int kk = 0; kk < 4; ++kk)
            acc[q][0] = __builtin_amdgcn_mfma_f32_16x16x32_bf16(Af1[kk], S[q * 4 + kk], acc[q][0], 0, 0, 0);
      }
      // ---- chunk S2: ch0 q2,3 ks4..7
      {
        bf16x8 S[8];
        #pragma unroll
        for (int i = 0; i < 8; ++i)
          S[i] = *(const bf16x8*)(sbase + (size_t)(16 + i) * 512 + l * 8);
        #pragma unroll
        for (int q = 2; q < 4; ++q)
          #pragma unroll
          for (int kk = 0; kk < 4; ++kk)
            acc[q][0] = __builtin_amdgcn_mfma_f32_16x16x32_bf16(Af1[kk], S[(q - 2) * 4 + kk], acc[q][0], 0, 0, 0);
      }
      // ---- chunk S3: ch1 q0,1 ks4..7
      {
        bf16x8 S[8];
        #pragma unroll
        for (int i = 0; i < 8; ++i)
          S[i] = *(const bf16x8*)(sbase + (size_t)(24 + i) * 512 + l * 8);
        #pragma unroll
        for (int q = 0; q < 2; ++q)
          #pragma unroll
          for (int kk = 0; kk < 4; ++kk)
            acc[q][1] = __builtin_amdgcn_mfma_f32_16x16x32_bf16(Af1[kk], S[q * 4 + kk], acc[q][1], 0, 0, 0);
      }
      // ---- chunk S4: ch1 q2,3 ks4..7
      {
        bf16x8 S[8];
        #pragma unroll
        for (int i = 0; i < 8; ++i)
          S[i] = *(const bf16x8*)(sbase + (size_t)(32 + i) * 512 + l * 8);
        #pragma unroll
        for (int q = 2; q < 4; ++q)
          #pragma unroll
          for (int kk = 0; kk < 4; ++kk)
            acc[q][1] = __builtin_amdgcn_mfma_f32_16x16x32_bf16(Af1[kk], S[(q - 2) * 4 + kk], acc[q][1], 0, 0, 0);
      }
    }

    // ---- activations; lane owns (b = half*16 + q4*4+r, col = j0 + ch*16 + l15)
    float hv[8];
    #pragma unroll
    for (int ch = 0; ch < 2; ++ch)
      #pragma unroll
      for (int r = 0; r < 4; ++r) {
        int ix = ch * 4 + r;
        float ig = sigf(acc[0][ch][r]);
        float fg = sigf(acc[1][ch][r]);
        float gg = tanhfast(acc[2][ch][r]);
        float og = sigf(acc[3][ch][r]);
        float c2 = fg * cst[ix] + ig * gg;
        cst[ix] = c2;
        hv[ix] = og * tanhfast(c2);
      }

    // ---- gates for t+1 (issued early; latency hides under next barrier+stream)
    if (t < SS - 1) {
      const int sn = d ? (SS - 2 - t) : (t + 1);
      const float* wgs = wg + ((size_t)d * 4096 + (size_t)sn * 32 + half * 16) * 1024 + j0 + l15;
      #pragma unroll
      for (int q = 0; q < 4; ++q)
        #pragma unroll
        for (int ch = 0; ch < 2; ++ch)
          #pragma unroll
          for (int r = 0; r < 4; ++r)
            acc[q][ch][r] = wgs[(size_t)(q4 * 4 + r) * 1024 + q * 256 + ch * 16];
    }

    // ---- publish h_t to LDS (swizzled: 16B-unit ^= row&7)
    {
      const int p = (t & 1) * 4096;
      #pragma unroll
      for (int ch = 0; ch < 2; ++ch)
        #pragma unroll
        for (int r = 0; r < 4; ++r) {
          int b = q4 * 4 + r;
          int col = j0 + ch * 16 + l15;
          hsh[p + b * 256 + (((col >> 3) ^ (b & 7)) * 8) + (col & 7)] = f2bf(hv[ch * 4 + r]);
        }
    }

    // ---- outh (non-temporal, off critical path)
    {
      float* op = outh + ((size_t)(s * 32 + half * 16)) * 512 + d * 256 + j0 + l15;
      #pragma unroll
      for (int ch = 0; ch < 2; ++ch)
        #pragma unroll
        for (int r = 0; r < 4; ++r)
          __builtin_nontemporal_store(hv[ch * 4 + r], op + (size_t)(q4 * 4 + r) * 512 + ch * 16);
    }
  }
}

// ---------------------------------------------------------------- K5: emit GEMM (tiny)
__global__ __launch_bounds__(64) void k5_emit(
    const float* __restrict__ outh, const float* __restrict__ eW,
    const float* __restrict__ eb, float* __restrict__ em) {
  int row = blockIdx.x;
  int t = threadIdx.x;
  if (t < TT) {
    const float4* o4 = (const float4*)(outh + (size_t)row * 512);
    const float4* w4 = (const float4*)(eW + (size_t)t * 512);
    float acc = 0.f;
    #pragma unroll 16
    for (int k = 0; k < 128; ++k) {
      float4 a = o4[k], bq = w4[k];
      acc += a.x * bq.x + a.y * bq.y + a.z * bq.z + a.w * bq.w;
    }
    em[row * TT + t] = acc + eb[t];
  }
}

// ---------------------------------------------------------------- K6: CRF NLL (32 independent batches)
__global__ __launch_bounds__(64) void k6_crf(
    const int* __restrict__ sentence, const int* __restrict__ tags,
    const float* __restrict__ em, const float* __restrict__ trans,
    const float* __restrict__ startv, const float* __restrict__ endv,
    float* __restrict__ outp) {
  int b = blockIdx.x;
  int j = threadIdx.x;
  __shared__ float ash[TT];
  __shared__ float red[TT];
  float tc[TT];
  float alpha = 0.f;
  if (j < TT) {
    #pragma unroll
    for (int i = 0; i < TT; ++i) tc[i] = trans[i * TT + j];
    alpha = startv[j] + em[(0 * BB + b) * TT + j];
  }
  for (int s = 1; s < SS; ++s) {
    if (j < TT) ash[j] = alpha;
    __syncthreads();
    int m = (sentence[s * BB + b] != 1) ? 1 : 0;
    if (j < TT) {
      float mx = -1e30f;
      #pragma unroll
      for (int i = 0; i < TT; ++i) mx = fmaxf(mx, ash[i] + tc[i]);
      float sum = 0.f;
      #pragma unroll
      for (int i = 0; i < TT; ++i) sum += __expf(ash[i] + tc[i] - mx);
      float nxt = mx + __logf(sum) + em[(s * BB + b) * TT + j];
      if (m) alpha = nxt;
    }
    __syncthreads();
  }
  if (j < TT) red[j] = alpha + endv[j];
  __syncthreads();
  if (j == 0) {
    float mx = -1e30f;
    for (int i = 0; i < TT; ++i) mx = fmaxf(mx, red[i]);
    float sum = 0.f;
    for (int i = 0; i < TT; ++i) sum += __expf(red[i] - mx);
    float den = mx + __logf(sum);
    int prev = tags[0 * BB + b];
    float num = startv[prev] + em[(0 * BB + b) * TT + prev];
    for (int s = 1; s < SS; ++s) {
      int tg = tags[s * BB + b];
      if (sentence[s * BB + b] != 1) {
        num += trans[prev * TT + tg] + em[(s * BB + b) * TT + tg];
        prev = tg;
      }
    }
    num += endv[prev];
    atomicAdd(outp, den - num);
  }
}

// ---------------------------------------------------------------- launcher
extern "C" void kernel_launch(void* const* d_in, const int* in_sizes, int n_in,
                              void* d_out, int out_size, void* d_ws, size_t ws_size,
                              hipStream_t stream) {
  (void)in_sizes; (void)n_in; (void)out_size; (void)ws_size;
  const int*   sentence = (const int*)d_in[0];
  const int*   charidx  = (const int*)d_in[1];
  const int*   tags     = (const int*)d_in[2];
  const float* Wwe   = (const float*)d_in[3];
  const float* Wce   = (const float*)d_in[4];
  const float* cWihF = (const float*)d_in[5];
  const float* cWhhF = (const float*)d_in[6];
  const float* cbF   = (const float*)d_in[7];
  const float* wWihF = (const float*)d_in[8];
  const float* wWhhF = (const float*)d_in[9];
  const float* wbF   = (const float*)d_in[10];
  const float* cWihB = (const float*)d_in[11];
  const float* cWhhB = (const float*)d_in[12];
  const float* cbB   = (const float*)d_in[13];
  const float* wWihB = (const float*)d_in[14];
  const float* wWhhB = (const float*)d_in[15];
  const float* wbB   = (const float*)d_in[16];
  const float* eW    = (const float*)d_in[17];
  const float* eb    = (const float*)d_in[18];
  const float* trans = (const float*)d_in[19];
  const float* startv= (const float*)d_in[20];
  const float* endv  = (const float*)d_in[21];

  char* ws = (char*)d_ws;
  float*          ihv   = (float*)(ws + 512);             //  204800 B
  float*          x     = (float*)(ws + 205312);          // 6291456 B
  float*          wg    = (float*)(ws + 6496768);         // 33554432 B
  float*          outh  = (float*)(ws + 40116736);        // 8388608 B
  float*          em    = (float*)(ws + 48505344);        //  278528 B
  // wstr (655360 B) aliases the head of the x region: x is dead after k3
  // reads it, and k3b (which writes wstr) launches AFTER k3.
  unsigned short* wstr  = (unsigned short*)(ws + 205312);
  // total ws usage: 48,783,872 B (unchanged)

  hipMemsetAsync(d_out, 0, sizeof(float), stream);

  k0_ihvocab<<<200, 256, 0, stream>>>(Wce, cWihF, cbF, cWihB, cbB, ihv);
  k1_char<<<512, 256, 0, stream>>>(charidx, cWhhF, cWhhB, ihv, x);
  k2_we<<<4096, 64, 0, stream>>>(sentence, Wwe, x);
  k3_ihgemm<<<dim3(16, 32), 256, 0, stream>>>(x, wWihF, wbF, wWihB, wbB, wg);
  k3b_pack<<<640, 64, 0, stream>>>(wWhhF, wWhhB, wstr);   // after k3: x is dead
  k4_word<<<4, 512, 0, stream>>>(wWhhF, wWhhB, wg, outh, wstr);
  k5_emit<<<4096, 64, 0, stream>>>(outh, eW, eb, em);
  k6_crf<<<32, 64, 0, stream>>>(sentence, tags, em, trans, startv, endv, (float*)d_out);
}

// Round 7
// 1369.493 us; speedup vs baseline: 1.2341x; 1.0110x over previous
//
#include <hip/hip_runtime.h>
#include <math.h>

#define SS 128
#define BB 32
#define CC 16
#define DW 256
#define DC 64
#define HC 128
#define KX 384   // DW + HC
#define TT 17

typedef __attribute__((ext_vector_type(8))) short bf16x8;
typedef __attribute__((ext_vector_type(4))) float f32x4;
typedef unsigned long long ull_t;

__device__ __forceinline__ float sigf(float x) { return 1.0f / (1.0f + __expf(-x)); }
__device__ __forceinline__ float tanhfast(float x) {
  float xc = fminf(fmaxf(x, -15.f), 15.f);
  float e = __expf(2.f * xc);
  return (e - 1.f) / (e + 1.f);
}
__device__ __forceinline__ unsigned short f2bf(float x) {
  unsigned int u = __float_as_uint(x);
  u += 0x7FFF + ((u >> 16) & 1);
  return (unsigned short)(u >> 16);
}

// ---------------------------------------------------------------- K0: char ih vocab table
__global__ __launch_bounds__(256) void k0_ihvocab(
    const float* __restrict__ Wce,
    const float* __restrict__ WihF, const float* __restrict__ bF,
    const float* __restrict__ WihB, const float* __restrict__ bB,
    float* __restrict__ ihv) {
  int blk = blockIdx.x;          // 0..199
  int d = blk / 100, v = blk % 100;
  const float* Wih = d ? WihB : WihF;
  const float* bb  = d ? bB   : bF;
  __shared__ float ce[DC];
  if (threadIdx.x < DC) ce[threadIdx.x] = Wce[v * DC + threadIdx.x];
  __syncthreads();
  int g = threadIdx.x;
  float acc = bb[g];
  #pragma unroll 16
  for (int k = 0; k < DC; ++k) acc += ce[k] * Wih[g * DC + k];
  ihv[(d * 100 + v) * 256 + g] = acc;
}

// ---------------------------------------------------------------- K1: char BiLSTM (per-chain, no global sync)
__global__ __launch_bounds__(256) void k1_char(
    const int* __restrict__ charidx,   // (B,S,C)
    const float* __restrict__ WhhF, const float* __restrict__ WhhB,
    const float* __restrict__ ihv,     // (2,100,256)
    float* __restrict__ x)             // (4096, 384)
{
  int blk = blockIdx.x;
  int d = blk >> 8;
  int n0 = (blk & 255) * 16;
  const float* Whh = d ? WhhB : WhhF;

  __shared__ float Wl[256 * 68];
  __shared__ float hl[16 * 68];

  for (int i = threadIdx.x; i < 256 * 64; i += 256) {
    int g = i >> 6, k = i & 63;
    Wl[g * 68 + k] = Whh[i];
  }
  __syncthreads();

  int hh = threadIdx.x & 63;
  int ng = threadIdx.x >> 6;
  float c[4] = {0.f, 0.f, 0.f, 0.f};
  float h[4] = {0.f, 0.f, 0.f, 0.f};
  int bb_[4], ss_[4];
  #pragma unroll
  for (int m = 0; m < 4; ++m) {
    int n = n0 + ng + 4 * m;
    bb_[m] = n >> 7; ss_[m] = n & 127;
  }

  for (int t = 0; t < CC; ++t) {
    int cpos = d ? (CC - 1 - t) : t;
    float acc[4][4];
    #pragma unroll
    for (int m = 0; m < 4; ++m) {
      int v = charidx[bb_[m] * (SS * CC) + ss_[m] * CC + cpos];
      const float* base = ihv + (d * 100 + v) * 256 + hh;
      acc[m][0] = base[0]; acc[m][1] = base[64]; acc[m][2] = base[128]; acc[m][3] = base[192];
    }
    if (t > 0) {
      #pragma unroll 4
      for (int k = 0; k < 64; k += 4) {
        float4 w4[4];
        #pragma unroll
        for (int q = 0; q < 4; ++q)
          w4[q] = *(const float4*)&Wl[(q * 64 + hh) * 68 + k];
        #pragma unroll
        for (int m = 0; m < 4; ++m) {
          float4 h4 = *(const float4*)&hl[(ng + 4 * m) * 68 + k];
          #pragma unroll
          for (int q = 0; q < 4; ++q)
            acc[m][q] += h4.x * w4[q].x + h4.y * w4[q].y + h4.z * w4[q].z + h4.w * w4[q].w;
        }
      }
      __syncthreads();
    }
    #pragma unroll
    for (int m = 0; m < 4; ++m) {
      float ig = sigf(acc[m][0]);
      float fg = sigf(acc[m][1]);
      float gg = tanhfast(acc[m][2]);
      float og = sigf(acc[m][3]);
      c[m] = fg * c[m] + ig * gg;
      h[m] = og * tanhfast(c[m]);
      hl[(ng + 4 * m) * 68 + hh] = h[m];
    }
    __syncthreads();
  }
  #pragma unroll
  for (int m = 0; m < 4; ++m) {
    int row = ss_[m] * BB + bb_[m];
    x[row * KX + d * 64 + hh] = h[m];
  }
}

// ---------------------------------------------------------------- K2: word embedding gather
__global__ __launch_bounds__(64) void k2_we(
    const int* __restrict__ sentence, const float* __restrict__ Wwe,
    float* __restrict__ x) {
  int row = blockIdx.x;
  int idx = sentence[row];
  const float4* src = (const float4*)(Wwe + (size_t)idx * DW);
  float4* dst = (float4*)(x + (size_t)row * KX + HC);
  dst[threadIdx.x] = src[threadIdx.x];
}

// ---------------------------------------------------------------- K3: word ih GEMM  wg[d][row][g]
__global__ __launch_bounds__(256) void k3_ihgemm(
    const float* __restrict__ x,
    const float* __restrict__ WihF, const float* __restrict__ bF,
    const float* __restrict__ WihB, const float* __restrict__ bB,
    float* __restrict__ wg) {
  int n0 = blockIdx.x * 128;
  int m0 = blockIdx.y * 128;
  int d  = n0 >> 10;
  int gb = n0 & 1023;
  const float* Wih  = d ? WihB : WihF;
  const float* bias = d ? bB   : bF;

  __shared__ float At[32][132];
  __shared__ float Bt[32][132];

  int tid = threadIdx.x;
  int half = tid & 1, r = tid >> 1;
  int tm = tid & 15, tn = tid >> 4;
  float acc[8][8] = {};

  for (int k0 = 0; k0 < KX; k0 += 32) {
    __syncthreads();
    {
      const float4* srcA = (const float4*)(x + (size_t)(m0 + r) * KX + k0 + half * 16);
      const float4* srcB = (const float4*)(Wih + (size_t)(gb + r) * KX + k0 + half * 16);
      #pragma unroll
      for (int q = 0; q < 4; ++q) {
        float4 v = srcA[q];
        int kk = half * 16 + q * 4;
        At[kk + 0][r] = v.x; At[kk + 1][r] = v.y; At[kk + 2][r] = v.z; At[kk + 3][r] = v.w;
      }
      #pragma unroll
      for (int q = 0; q < 4; ++q) {
        float4 v = srcB[q];
        int kk = half * 16 + q * 4;
        Bt[kk + 0][r] = v.x; Bt[kk + 1][r] = v.y; Bt[kk + 2][r] = v.z; Bt[kk + 3][r] = v.w;
      }
    }
    __syncthreads();
    #pragma unroll 8
    for (int k = 0; k < 32; ++k) {
      float4 a0 = *(const float4*)&At[k][tm * 8];
      float4 a1 = *(const float4*)&At[k][tm * 8 + 4];
      float4 b0 = *(const float4*)&Bt[k][tn * 8];
      float4 b1 = *(const float4*)&Bt[k][tn * 8 + 4];
      float av[8] = {a0.x, a0.y, a0.z, a0.w, a1.x, a1.y, a1.z, a1.w};
      float bv[8] = {b0.x, b0.y, b0.z, b0.w, b1.x, b1.y, b1.z, b1.w};
      #pragma unroll
      for (int i = 0; i < 8; ++i)
        #pragma unroll
        for (int jq = 0; jq < 8; ++jq)
          acc[i][jq] += av[i] * bv[jq];
    }
  }
  float bv8[8];
  #pragma unroll
  for (int jq = 0; jq < 8; ++jq) bv8[jq] = bias[gb + tn * 8 + jq];
  #pragma unroll
  for (int i = 0; i < 8; ++i) {
    int m = m0 + tm * 8 + i;
    float* dst = wg + ((size_t)(d * 4096 + m)) * 1024 + gb + tn * 8;
    float4 v0 = {acc[i][0] + bv8[0], acc[i][1] + bv8[1], acc[i][2] + bv8[2], acc[i][3] + bv8[3]};
    float4 v1 = {acc[i][4] + bv8[4], acc[i][5] + bv8[5], acc[i][6] + bv8[6], acc[i][7] + bv8[7]};
    *(float4*)dst = v0; *(float4*)(dst + 4) = v1;
  }
}

// ---------------------------------------------------------------- K3b: pack streamed Whh frags (48 per (d,wave)) as bf16
// Chunk-major order, 12 chunks x 4 frags per (d,w):
//   chunk 0..3 : ch0, q=chunk,    ks=j        (pairs Af0)
//   chunk 4..7 : ch0, q=chunk-4,  ks=4+j      (pairs Af1)
//   chunk 8..11: ch1, q=chunk-8,  ks=4+j      (pairs Af1)
// wstr[((d*8+w)*48 + chunk*4+j)*512 + lane*8]
__global__ __launch_bounds__(64) void k3b_pack(
    const float* __restrict__ WhhF, const float* __restrict__ WhhB,
    unsigned short* __restrict__ wstr) {
  int bid = blockIdx.x;            // 0..767
  int fidx = bid % 48;
  int dw = bid / 48;               // 0..15
  int d = dw >> 3, w = dw & 7;
  int chunk = fidx >> 2, j = fidx & 3;
  int ch, q, ks;
  if (chunk < 4)      { ch = 0; q = chunk;     ks = j; }
  else if (chunk < 8) { ch = 0; q = chunk - 4; ks = 4 + j; }
  else                { ch = 1; q = chunk - 8; ks = 4 + j; }
  const float* Whh = d ? WhhB : WhhF;
  int l = threadIdx.x, l15 = l & 15, q4 = l >> 4;
  const float* wr = Whh + (size_t)(q * 256 + w * 32 + ch * 16 + l15) * 256 + ks * 32 + q4 * 8;
  float4 lo = *(const float4*)(wr);
  float4 hi = *(const float4*)(wr + 4);
  bf16x8 f;
  f[0] = (short)f2bf(lo.x); f[1] = (short)f2bf(lo.y);
  f[2] = (short)f2bf(lo.z); f[3] = (short)f2bf(lo.w);
  f[4] = (short)f2bf(hi.x); f[5] = (short)f2bf(hi.y);
  f[6] = (short)f2bf(hi.z); f[7] = (short)f2bf(hi.w);
  *(bf16x8*)(wstr + (size_t)bid * 512 + l * 8) = f;
}

// ---------------------------------------------------------------- K4: word BiLSTM recurrence (batch-split, barrier-synced, L2-stream)
// 4 WGs = 2 dir x 2 batch-halves; 8 waves x 512 thr; wave owns cols
// j0=w*32..+31 x 4 gates (M=16, K=256 -> 64 MFMA/wave/step).
// ZERO-SPILL 128-VGPR budget (round-6 post-mortem: Bf-resident version
// spilled in the hot loop -> 44% VALUBusy/CU of scratch/addr ops):
//   LDS-resident:  ch1 ks0..3 (16 frags/wave, 128KB/WG, loaded once)
//   L2-streamed:   ch0 ks0..7 + ch1 ks4..7 = 48 frags/wave/step, consumed
//                  as 12 chunks of 4 frags through TWO alternating 16-reg
//                  buffers (Sa/Sb): MFMA chunk c while c+1 in flight and
//                  c+2 issuing -> compiler emits counted vmcnt(4) waits.
// Live set: Sa16+Sb16+Af32+acc32+cst8+misc ~= 116 < 128 -> no spill.
// h exchange: LDS double-buffer + lgkm-only barrier (global loads stay in
// flight across it). No atomics, no cross-WG traffic.
__global__
__attribute__((amdgpu_flat_work_group_size(512, 512)))
void k4_word(
    const float* __restrict__ WhhF, const float* __restrict__ WhhB,
    const float* __restrict__ wg,           // (2,4096,1024) f32
    float* __restrict__ outh,               // (4096,512) f32
    const unsigned short* __restrict__ wstr) {
  const int blk = blockIdx.x;               // 0..3
  const int d = blk >> 1, half = blk & 1;
  const int tid = threadIdx.x;
  const int w = tid >> 6;                   // wave 0..7
  const int l = tid & 63;
  const int l15 = l & 15, q4 = l >> 4;
  const int j0 = w * 32;
  const float* __restrict__ Whh = d ? WhhB : WhhF;

  __shared__ unsigned short ldsw[8 * 16 * 64 * 8];   // 131072 B: ch1 ks0..3 weight frags
  __shared__ unsigned short hsh[2 * 16 * 256];       // 16384 B: h double-buffer (swizzled)

  // ---- LDS weights: ch=1 (cols j0+16..j0+31), ks=0..3 (one-time, wave-own)
  #pragma unroll
  for (int q = 0; q < 4; ++q) {
    const float* wr = Whh + (size_t)(q * 256 + j0 + 16 + l15) * 256 + q4 * 8;
    #pragma unroll
    for (int ks = 0; ks < 4; ++ks) {
      float4 lo = *(const float4*)(wr + ks * 32);
      float4 hi = *(const float4*)(wr + ks * 32 + 4);
      bf16x8 f;
      f[0] = (short)f2bf(lo.x); f[1] = (short)f2bf(lo.y);
      f[2] = (short)f2bf(lo.z); f[3] = (short)f2bf(lo.w);
      f[4] = (short)f2bf(hi.x); f[5] = (short)f2bf(hi.y);
      f[6] = (short)f2bf(hi.z); f[7] = (short)f2bf(hi.w);
      *(bf16x8*)&ldsw[((w * 16 + q * 4 + ks) * 64 + l) * 8] = f;
    }
  }

  const unsigned short* sb = wstr + (size_t)(d * 8 + w) * (48 * 512);

  auto loadc = [&](bf16x8* Sx, int c) {
    #pragma unroll
    for (int j = 0; j < 4; ++j)
      Sx[j] = *(const bf16x8*)(sb + (size_t)(c * 4 + j) * 512 + l * 8);
  };
  auto mf4 = [&](f32x4& a, const bf16x8* Af, const bf16x8* Sx) {
    #pragma unroll
    for (int j = 0; j < 4; ++j)
      a = __builtin_amdgcn_mfma_f32_16x16x32_bf16(Af[j], Sx[j], a, 0, 0, 0);
  };

  f32x4 acc[4][2];
  float cst[8];
  #pragma unroll
  for (int i = 0; i < 8; ++i) cst[i] = 0.f;

  // ---- prologue: gates for t=0
  {
    const int s0 = d ? (SS - 1) : 0;
    const float* wgs = wg + ((size_t)d * 4096 + (size_t)s0 * 32 + half * 16) * 1024 + j0 + l15;
    #pragma unroll
    for (int q = 0; q < 4; ++q)
      #pragma unroll
      for (int ch = 0; ch < 2; ++ch)
        #pragma unroll
        for (int r = 0; r < 4; ++r)
          acc[q][ch][r] = wgs[(size_t)(q4 * 4 + r) * 1024 + q * 256 + ch * 16];
  }

  #pragma unroll 1
  for (int t = 0; t < SS; ++t) {
    const int s = d ? (SS - 1 - t) : t;

    if (t > 0) {
      // ---- chunks 0,1 issued pre-barrier (hide under barrier + LDS phase)
      bf16x8 Sa[4], Sb[4];
      loadc(Sa, 0);
      loadc(Sb, 1);
      // ---- lgkm-only barrier: ds publishes drained; global loads in flight
      __builtin_amdgcn_sched_barrier(0);
      asm volatile("s_waitcnt lgkmcnt(0)" ::: "memory");
      __builtin_amdgcn_s_barrier();
      __builtin_amdgcn_sched_barrier(0);
      const int pr = ((t - 1) & 1) * 4096;
      // ---- A-fragments ks0..3
      bf16x8 Af0[4];
      #pragma unroll
      for (int ks = 0; ks < 4; ++ks)
        Af0[ks] = *(const bf16x8*)&hsh[pr + l15 * 256 + (((ks * 4 + q4) ^ (l15 & 7)) * 8)];
      // ---- LDS weight phase: ch1 ks0..3 (covers chunk0/1 flight time)
      #pragma unroll
      for (int q = 0; q < 4; ++q)
        #pragma unroll
        for (int ks = 0; ks < 4; ++ks) {
          bf16x8 bw = *(const bf16x8*)&ldsw[((w * 16 + q * 4 + ks) * 64 + l) * 8];
          acc[q][1] = __builtin_amdgcn_mfma_f32_16x16x32_bf16(Af0[ks], bw, acc[q][1], 0, 0, 0);
        }
      // ---- streamed chunks, 2-deep pipelined through Sa/Sb
      mf4(acc[0][0], Af0, Sa);  loadc(Sa, 2);   // chunk0 done, issue chunk2
      mf4(acc[1][0], Af0, Sb);  loadc(Sb, 3);
      mf4(acc[2][0], Af0, Sa);  loadc(Sa, 4);
      mf4(acc[3][0], Af0, Sb);  loadc(Sb, 5);
      bf16x8 Af1[4];
      #pragma unroll
      for (int ks = 0; ks < 4; ++ks)
        Af1[ks] = *(const bf16x8*)&hsh[pr + l15 * 256 + ((((ks + 4) * 4 + q4) ^ (l15 & 7)) * 8)];
      mf4(acc[0][0], Af1, Sa);  loadc(Sa, 6);
      mf4(acc[1][0], Af1, Sb);  loadc(Sb, 7);
      mf4(acc[2][0], Af1, Sa);  loadc(Sa, 8);
      mf4(acc[3][0], Af1, Sb);  loadc(Sb, 9);
      mf4(acc[0][1], Af1, Sa);  loadc(Sa, 10);
      mf4(acc[1][1], Af1, Sb);  loadc(Sb, 11);
      mf4(acc[2][1], Af1, Sa);
      mf4(acc[3][1], Af1, Sb);
    }

    // ---- activations; lane owns (b = half*16 + q4*4+r, col = j0 + ch*16 + l15)
    float hv[8];
    #pragma unroll
    for (int ch = 0; ch < 2; ++ch)
      #pragma unroll
      for (int r = 0; r < 4; ++r) {
        int ix = ch * 4 + r;
        float ig = sigf(acc[0][ch][r]);
        float fg = sigf(acc[1][ch][r]);
        float gg = tanhfast(acc[2][ch][r]);
        float og = sigf(acc[3][ch][r]);
        float c2 = fg * cst[ix] + ig * gg;
        cst[ix] = c2;
        hv[ix] = og * tanhfast(c2);
      }

    // ---- gates for t+1 (issued early; latency hides under next barrier+stream)
    if (t < SS - 1) {
      const int sn = d ? (SS - 2 - t) : (t + 1);
      const float* wgs = wg + ((size_t)d * 4096 + (size_t)sn * 32 + half * 16) * 1024 + j0 + l15;
      #pragma unroll
      for (int q = 0; q < 4; ++q)
        #pragma unroll
        for (int ch = 0; ch < 2; ++ch)
          #pragma unroll
          for (int r = 0; r < 4; ++r)
            acc[q][ch][r] = wgs[(size_t)(q4 * 4 + r) * 1024 + q * 256 + ch * 16];
    }

    // ---- publish h_t to LDS (swizzled: 16B-unit ^= row&7)
    {
      const int p = (t & 1) * 4096;
      #pragma unroll
      for (int ch = 0; ch < 2; ++ch)
        #pragma unroll
        for (int r = 0; r < 4; ++r) {
          int b = q4 * 4 + r;
          int col = j0 + ch * 16 + l15;
          hsh[p + b * 256 + (((col >> 3) ^ (b & 7)) * 8) + (col & 7)] = f2bf(hv[ch * 4 + r]);
        }
    }

    // ---- outh (non-temporal, off critical path)
    {
      float* op = outh + ((size_t)(s * 32 + half * 16)) * 512 + d * 256 + j0 + l15;
      #pragma unroll
      for (int ch = 0; ch < 2; ++ch)
        #pragma unroll
        for (int r = 0; r < 4; ++r)
          __builtin_nontemporal_store(hv[ch * 4 + r], op + (size_t)(q4 * 4 + r) * 512 + ch * 16);
    }
  }
}

// ---------------------------------------------------------------- K5: emit GEMM (tiny)
__global__ __launch_bounds__(64) void k5_emit(
    const float* __restrict__ outh, const float* __restrict__ eW,
    const float* __restrict__ eb, float* __restrict__ em) {
  int row = blockIdx.x;
  int t = threadIdx.x;
  if (t < TT) {
    const float4* o4 = (const float4*)(outh + (size_t)row * 512);
    const float4* w4 = (const float4*)(eW + (size_t)t * 512);
    float acc = 0.f;
    #pragma unroll 16
    for (int k = 0; k < 128; ++k) {
      float4 a = o4[k], bq = w4[k];
      acc += a.x * bq.x + a.y * bq.y + a.z * bq.z + a.w * bq.w;
    }
    em[row * TT + t] = acc + eb[t];
  }
}

// ---------------------------------------------------------------- K6: CRF NLL (32 independent batches)
__global__ __launch_bounds__(64) void k6_crf(
    const int* __restrict__ sentence, const int* __restrict__ tags,
    const float* __restrict__ em, const float* __restrict__ trans,
    const float* __restrict__ startv, const float* __restrict__ endv,
    float* __restrict__ outp) {
  int b = blockIdx.x;
  int j = threadIdx.x;
  __shared__ float ash[TT];
  __shared__ float red[TT];
  float tc[TT];
  float alpha = 0.f;
  if (j < TT) {
    #pragma unroll
    for (int i = 0; i < TT; ++i) tc[i] = trans[i * TT + j];
    alpha = startv[j] + em[(0 * BB + b) * TT + j];
  }
  for (int s = 1; s < SS; ++s) {
    if (j < TT) ash[j] = alpha;
    __syncthreads();
    int m = (sentence[s * BB + b] != 1) ? 1 : 0;
    if (j < TT) {
      float mx = -1e30f;
      #pragma unroll
      for (int i = 0; i < TT; ++i) mx = fmaxf(mx, ash[i] + tc[i]);
      float sum = 0.f;
      #pragma unroll
      for (int i = 0; i < TT; ++i) sum += __expf(ash[i] + tc[i] - mx);
      float nxt = mx + __logf(sum) + em[(s * BB + b) * TT + j];
      if (m) alpha = nxt;
    }
    __syncthreads();
  }
  if (j < TT) red[j] = alpha + endv[j];
  __syncthreads();
  if (j == 0) {
    float mx = -1e30f;
    for (int i = 0; i < TT; ++i) mx = fmaxf(mx, red[i]);
    float sum = 0.f;
    for (int i = 0; i < TT; ++i) sum += __expf(red[i] - mx);
    float den = mx + __logf(sum);
    int prev = tags[0 * BB + b];
    float num = startv[prev] + em[(0 * BB + b) * TT + prev];
    for (int s = 1; s < SS; ++s) {
      int tg = tags[s * BB + b];
      if (sentence[s * BB + b] != 1) {
        num += trans[prev * TT + tg] + em[(s * BB + b) * TT + tg];
        prev = tg;
      }
    }
    num += endv[prev];
    atomicAdd(outp, den - num);
  }
}

// ---------------------------------------------------------------- launcher
extern "C" void kernel_launch(void* const* d_in, const int* in_sizes, int n_in,
                              void* d_out, int out_size, void* d_ws, size_t ws_size,
                              hipStream_t stream) {
  (void)in_sizes; (void)n_in; (void)out_size; (void)ws_size;
  const int*   sentence = (const int*)d_in[0];
  const int*   charidx  = (const int*)d_in[1];
  const int*   tags     = (const int*)d_in[2];
  const float* Wwe   = (const float*)d_in[3];
  const float* Wce   = (const float*)d_in[4];
  const float* cWihF = (const float*)d_in[5];
  const float* cWhhF = (const float*)d_in[6];
  const float* cbF   = (const float*)d_in[7];
  const float* wWihF = (const float*)d_in[8];
  const float* wWhhF = (const float*)d_in[9];
  const float* wbF   = (const float*)d_in[10];
  const float* cWihB = (const float*)d_in[11];
  const float* cWhhB = (const float*)d_in[12];
  const float* cbB   = (const float*)d_in[13];
  const float* wWihB = (const float*)d_in[14];
  const float* wWhhB = (const float*)d_in[15];
  const float* wbB   = (const float*)d_in[16];
  const float* eW    = (const float*)d_in[17];
  const float* eb    = (const float*)d_in[18];
  const float* trans = (const float*)d_in[19];
  const float* startv= (const float*)d_in[20];
  const float* endv  = (const float*)d_in[21];

  char* ws = (char*)d_ws;
  float*          ihv   = (float*)(ws + 512);             //  204800 B
  float*          x     = (float*)(ws + 205312);          // 6291456 B
  float*          wg    = (float*)(ws + 6496768);         // 33554432 B
  float*          outh  = (float*)(ws + 40116736);        // 8388608 B
  float*          em    = (float*)(ws + 48505344);        //  278528 B
  // wstr (786432 B) aliases the head of the x region: x is dead after k3
  // reads it, and k3b (which writes wstr) launches AFTER k3.
  unsigned short* wstr  = (unsigned short*)(ws + 205312);
  // total ws usage: 48,783,872 B (unchanged)

  hipMemsetAsync(d_out, 0, sizeof(float), stream);

  k0_ihvocab<<<200, 256, 0, stream>>>(Wce, cWihF, cbF, cWihB, cbB, ihv);
  k1_char<<<512, 256, 0, stream>>>(charidx, cWhhF, cWhhB, ihv, x);
  k2_we<<<4096, 64, 0, stream>>>(sentence, Wwe, x);
  k3_ihgemm<<<dim3(16, 32), 256, 0, stream>>>(x, wWihF, wbF, wWihB, wbB, wg);
  k3b_pack<<<768, 64, 0, stream>>>(wWhhF, wWhhB, wstr);   // after k3: x is dead
  k4_word<<<4, 512, 0, stream>>>(wWhhF, wWhhB, wg, outh, wstr);
  k5_emit<<<4096, 64, 0, stream>>>(outh, eW, eb, em);
  k6_crf<<<32, 64, 0, stream>>>(sentence, tags, em, trans, startv, endv, (float*)d_out);
}

// Round 8
// 1016.551 us; speedup vs baseline: 1.6625x; 1.3472x over previous
//
#include <hip/hip_runtime.h>
#include <math.h>

#define SS 128
#define BB 32
#define CC 16
#define DW 256
#define DC 64
#define HC 128
#define KX 384   // DW + HC
#define TT 17

typedef __attribute__((ext_vector_type(8))) short bf16x8;
typedef __attribute__((ext_vector_type(4))) float f32x4;
typedef unsigned long long ull_t;

__device__ __forceinline__ float sigf(float x) { return 1.0f / (1.0f + __expf(-x)); }
__device__ __forceinline__ float tanhfast(float x) {
  float xc = fminf(fmaxf(x, -15.f), 15.f);
  float e = __expf(2.f * xc);
  return (e - 1.f) / (e + 1.f);
}
__device__ __forceinline__ unsigned short f2bf(float x) {
  unsigned int u = __float_as_uint(x);
  u += 0x7FFF + ((u >> 16) & 1);
  return (unsigned short)(u >> 16);
}
// Relaxed agent-scope atomics ONLY (native 32/64-bit, cache-bypassing; no fences).
__device__ __forceinline__ unsigned ld_u32(const unsigned* p) {
  return __hip_atomic_load(p, __ATOMIC_RELAXED, __HIP_MEMORY_SCOPE_AGENT);
}
__device__ __forceinline__ void st_u32(unsigned* p, unsigned v) {
  __hip_atomic_store(p, v, __ATOMIC_RELAXED, __HIP_MEMORY_SCOPE_AGENT);
}
__device__ __forceinline__ ull_t ld_ull(const ull_t* p) {
  return __hip_atomic_load(p, __ATOMIC_RELAXED, __HIP_MEMORY_SCOPE_AGENT);
}
__device__ __forceinline__ void st_ull(ull_t* p, ull_t v) {
  __hip_atomic_store(p, v, __ATOMIC_RELAXED, __HIP_MEMORY_SCOPE_AGENT);
}

// ---------------------------------------------------------------- K0: char ih vocab table
__global__ __launch_bounds__(256) void k0_ihvocab(
    const float* __restrict__ Wce,
    const float* __restrict__ WihF, const float* __restrict__ bF,
    const float* __restrict__ WihB, const float* __restrict__ bB,
    float* __restrict__ ihv) {
  int blk = blockIdx.x;          // 0..199
  int d = blk / 100, v = blk % 100;
  const float* Wih = d ? WihB : WihF;
  const float* bb  = d ? bB   : bF;
  __shared__ float ce[DC];
  if (threadIdx.x < DC) ce[threadIdx.x] = Wce[v * DC + threadIdx.x];
  __syncthreads();
  int g = threadIdx.x;
  float acc = bb[g];
  #pragma unroll 16
  for (int k = 0; k < DC; ++k) acc += ce[k] * Wih[g * DC + k];
  ihv[(d * 100 + v) * 256 + g] = acc;
}

// ---------------------------------------------------------------- K1: char BiLSTM (per-chain, no global sync)
// Wl layout: row g (0..255) of 64 floats, stored as 16 float4-chunks with
// chunk c placed at c ^ (g & 15)  (XOR swizzle, stride exactly 64 floats).
// Old layout (stride 68) had an 8-way bank conflict on every ds_read_b128
// (lane start-bank = 4*hh mod 32): ~35cy/read. Swizzled: each 8-lane group
// tiles all 32 banks -> optimal ~12cy. Same values, pure layout change.
__global__ __launch_bounds__(256) void k1_char(
    const int* __restrict__ charidx,   // (B,S,C)
    const float* __restrict__ WhhF, const float* __restrict__ WhhB,
    const float* __restrict__ ihv,     // (2,100,256)
    float* __restrict__ x)             // (4096, 384)
{
  int blk = blockIdx.x;
  int d = blk >> 8;
  int n0 = (blk & 255) * 16;
  const float* Whh = d ? WhhB : WhhF;

  __shared__ float Wl[256 * 64];
  __shared__ float hl[16 * 68];

  for (int i = threadIdx.x; i < 256 * 64; i += 256) {
    int g = i >> 6, k = i & 63;
    Wl[g * 64 + (((k >> 2) ^ (g & 15)) << 2) + (k & 3)] = Whh[i];
  }
  __syncthreads();

  int hh = threadIdx.x & 63;
  int ng = threadIdx.x >> 6;
  float c[4] = {0.f, 0.f, 0.f, 0.f};
  float h[4] = {0.f, 0.f, 0.f, 0.f};
  int bb_[4], ss_[4];
  #pragma unroll
  for (int m = 0; m < 4; ++m) {
    int n = n0 + ng + 4 * m;
    bb_[m] = n >> 7; ss_[m] = n & 127;
  }

  for (int t = 0; t < CC; ++t) {
    int cpos = d ? (CC - 1 - t) : t;
    float acc[4][4];
    #pragma unroll
    for (int m = 0; m < 4; ++m) {
      int v = charidx[bb_[m] * (SS * CC) + ss_[m] * CC + cpos];
      const float* base = ihv + (d * 100 + v) * 256 + hh;
      acc[m][0] = base[0]; acc[m][1] = base[64]; acc[m][2] = base[128]; acc[m][3] = base[192];
    }
    if (t > 0) {
      #pragma unroll 4
      for (int k = 0; k < 64; k += 4) {
        int kc = k >> 2;
        float4 w4[4];
        #pragma unroll
        for (int q = 0; q < 4; ++q)
          w4[q] = *(const float4*)&Wl[(q * 64 + hh) * 64 + ((kc ^ (hh & 15)) << 2)];
        #pragma unroll
        for (int m = 0; m < 4; ++m) {
          float4 h4 = *(const float4*)&hl[(ng + 4 * m) * 68 + k];
          #pragma unroll
          for (int q = 0; q < 4; ++q)
            acc[m][q] += h4.x * w4[q].x + h4.y * w4[q].y + h4.z * w4[q].z + h4.w * w4[q].w;
        }
      }
      __syncthreads();
    }
    #pragma unroll
    for (int m = 0; m < 4; ++m) {
      float ig = sigf(acc[m][0]);
      float fg = sigf(acc[m][1]);
      float gg = tanhfast(acc[m][2]);
      float og = sigf(acc[m][3]);
      c[m] = fg * c[m] + ig * gg;
      h[m] = og * tanhfast(c[m]);
      hl[(ng + 4 * m) * 68 + hh] = h[m];
    }
    __syncthreads();
  }
  #pragma unroll
  for (int m = 0; m < 4; ++m) {
    int row = ss_[m] * BB + bb_[m];
    x[row * KX + d * 64 + hh] = h[m];
  }
}

// ---------------------------------------------------------------- K2: word embedding gather
__global__ __launch_bounds__(64) void k2_we(
    const int* __restrict__ sentence, const float* __restrict__ Wwe,
    float* __restrict__ x) {
  int row = blockIdx.x;
  int idx = sentence[row];
  const float4* src = (const float4*)(Wwe + (size_t)idx * DW);
  float4* dst = (float4*)(x + (size_t)row * KX + HC);
  dst[threadIdx.x] = src[threadIdx.x];
}

// ---------------------------------------------------------------- K3: word ih GEMM  wg[d][row][g]
__global__ __launch_bounds__(256) void k3_ihgemm(
    const float* __restrict__ x,
    const float* __restrict__ WihF, const float* __restrict__ bF,
    const float* __restrict__ WihB, const float* __restrict__ bB,
    float* __restrict__ wg) {
  int n0 = blockIdx.x * 128;
  int m0 = blockIdx.y * 128;
  int d  = n0 >> 10;
  int gb = n0 & 1023;
  const float* Wih  = d ? WihB : WihF;
  const float* bias = d ? bB   : bF;

  __shared__ float At[32][132];
  __shared__ float Bt[32][132];

  int tid = threadIdx.x;
  int half = tid & 1, r = tid >> 1;
  int tm = tid & 15, tn = tid >> 4;
  float acc[8][8] = {};

  for (int k0 = 0; k0 < KX; k0 += 32) {
    __syncthreads();
    {
      const float4* srcA = (const float4*)(x + (size_t)(m0 + r) * KX + k0 + half * 16);
      const float4* srcB = (const float4*)(Wih + (size_t)(gb + r) * KX + k0 + half * 16);
      #pragma unroll
      for (int q = 0; q < 4; ++q) {
        float4 v = srcA[q];
        int kk = half * 16 + q * 4;
        At[kk + 0][r] = v.x; At[kk + 1][r] = v.y; At[kk + 2][r] = v.z; At[kk + 3][r] = v.w;
      }
      #pragma unroll
      for (int q = 0; q < 4; ++q) {
        float4 v = srcB[q];
        int kk = half * 16 + q * 4;
        Bt[kk + 0][r] = v.x; Bt[kk + 1][r] = v.y; Bt[kk + 2][r] = v.z; Bt[kk + 3][r] = v.w;
      }
    }
    __syncthreads();
    #pragma unroll 8
    for (int k = 0; k < 32; ++k) {
      float4 a0 = *(const float4*)&At[k][tm * 8];
      float4 a1 = *(const float4*)&At[k][tm * 8 + 4];
      float4 b0 = *(const float4*)&Bt[k][tn * 8];
      float4 b1 = *(const float4*)&Bt[k][tn * 8 + 4];
      float av[8] = {a0.x, a0.y, a0.z, a0.w, a1.x, a1.y, a1.z, a1.w};
      float bv[8] = {b0.x, b0.y, b0.z, b0.w, b1.x, b1.y, b1.z, b1.w};
      #pragma unroll
      for (int i = 0; i < 8; ++i)
        #pragma unroll
        for (int jq = 0; jq < 8; ++jq)
          acc[i][jq] += av[i] * bv[jq];
    }
  }
  float bv8[8];
  #pragma unroll
  for (int jq = 0; jq < 8; ++jq) bv8[jq] = bias[gb + tn * 8 + jq];
  #pragma unroll
  for (int i = 0; i < 8; ++i) {
    int m = m0 + tm * 8 + i;
    float* dst = wg + ((size_t)(d * 4096 + m)) * 1024 + gb + tn * 8;
    float4 v0 = {acc[i][0] + bv8[0], acc[i][1] + bv8[1], acc[i][2] + bv8[2], acc[i][3] + bv8[3]};
    float4 v1 = {acc[i][4] + bv8[4], acc[i][5] + bv8[5], acc[i][6] + bv8[6], acc[i][7] + bv8[7]};
    *(float4*)dst = v0; *(float4*)(dst + 4) = v1;
  }
}

// ---------------------------------------------------------------- K4: word BiLSTM recurrence (round-0 global-flag design, 523us proven)
// 32 WGs x 64 threads (1 wave each), 16 waves per direction. Wave widx owns
// h-cols j0w..j0w+15 (x4 gate blocks). Whh in 128 VGPRs as bf16 B-frags
// (64-thr blocks get a >=144 VGPR budget on this toolchain; 512-thr blocks
// are pinned at 128 -- rounds 2-7 evidence). Protocol: relaxed 64-bit
// cache-bypassing atomics + per-wave tag words. ~3 coherence RTs/step is
// the measured floor for cross-CU sync (rounds 0/1 probes).
__global__ __launch_bounds__(64, 1) void k4_word(
    const float* __restrict__ WhhF, const float* __restrict__ WhhB,
    const float* __restrict__ wg,           // (2,4096,1024) f32
    float* __restrict__ outh,               // (4096,512) f32
    unsigned short* __restrict__ hbuf,      // (2 dir, 2 parity, 32 b, 256 k) bf16
    unsigned int* __restrict__ flags) {     // per dir: 16 tags at dir*16
  const int blk = blockIdx.x;               // 0..31
  const int d = blk >> 4, widx = blk & 15;
  const int l = threadIdx.x;                // 0..63
  const int l15 = l & 15, q4 = l >> 4;
  const int j0w = widx * 16;
  const float* __restrict__ Whh = d ? WhhB : WhhF;
  unsigned short* hb_d = hbuf + d * 16384;  // 2 parities * 8192
  unsigned int* fl = flags + d * 16;

  __shared__ unsigned short hl[32 * 24];    // per-wave transpose tile, row stride 48B

  // ---- Whh B-fragments resident: lane holds B[k=ks*32+q4*8+j][n=l15]
  bf16x8 Bf[4][8];
  #pragma unroll
  for (int q = 0; q < 4; ++q) {
    const float* wr = Whh + (size_t)(q * 256 + j0w + l15) * 256 + q4 * 8;
    #pragma unroll
    for (int ks = 0; ks < 8; ++ks) {
      float4 lo = *(const float4*)(wr + ks * 32);
      float4 hi = *(const float4*)(wr + ks * 32 + 4);
      bf16x8 f;
      f[0] = (short)f2bf(lo.x); f[1] = (short)f2bf(lo.y);
      f[2] = (short)f2bf(lo.z); f[3] = (short)f2bf(lo.w);
      f[4] = (short)f2bf(hi.x); f[5] = (short)f2bf(hi.y);
      f[6] = (short)f2bf(hi.z); f[7] = (short)f2bf(hi.w);
      Bf[q][ks] = f;
    }
  }

  float cst[8];
  #pragma unroll
  for (int i = 0; i < 8; ++i) cst[i] = 0.f;

  const int rb = l >> 1;          // transpose-read row (batch) 0..31
  const int rh = l & 1;           // transpose-read half-chunk

  for (int t = 0; t < SS; ++t) {
    const int s = d ? (SS - 1 - t) : t;

    // ---- ih gates into MFMA C-layout (issued before the wait; overlaps poll)
    f32x4 acc[4][2];
    const float* wgs = wg + ((size_t)d * 4096 + (size_t)s * 32) * 1024 + j0w + l15;
    #pragma unroll
    for (int q = 0; q < 4; ++q)
      #pragma unroll
      for (int mt = 0; mt < 2; ++mt)
        #pragma unroll
        for (int r = 0; r < 4; ++r)
          acc[q][mt][r] = wgs[(size_t)(q4 * 4 + r + mt * 16) * 1024 + q * 256];

    if (t > 0) {
      // ---- wait for all 16 producer waves of this direction (relaxed polls)
      for (;;) {
        unsigned tg = ld_u32(fl + l15);
        if (__all((int)(tg >= (unsigned)t))) break;
        __builtin_amdgcn_s_sleep(1);
      }

      // ---- A-fragments of h_{t-1}: cache-bypassing 8B loads
      const unsigned short* hp = hb_d + ((t - 1) & 1) * 8192 + q4 * 8;
      bf16x8 Af[2][8];
      #pragma unroll
      for (int mt = 0; mt < 2; ++mt)
        #pragma unroll
        for (int ks = 0; ks < 8; ++ks) {
          const ull_t* p = (const ull_t*)(hp + (size_t)(l15 + mt * 16) * 256 + ks * 32);
          union { ull_t u[2]; bf16x8 v; } cvt;
          cvt.u[0] = ld_ull(p);
          cvt.u[1] = ld_ull(p + 1);
          Af[mt][ks] = cvt.v;
        }
      #pragma unroll
      for (int q = 0; q < 4; ++q)
        #pragma unroll
        for (int mt = 0; mt < 2; ++mt) {
          f32x4 c = acc[q][mt];
          #pragma unroll
          for (int ks = 0; ks < 8; ++ks)
            c = __builtin_amdgcn_mfma_f32_16x16x32_bf16(Af[mt][ks], Bf[q][ks], c, 0, 0, 0);
          acc[q][mt] = c;
        }
    }

    // ---- activations; lane owns (b = q4*4+r+mt*16, col = j0w+l15)
    float hv[8];
    #pragma unroll
    for (int mt = 0; mt < 2; ++mt)
      #pragma unroll
      for (int r = 0; r < 4; ++r) {
        int ix = mt * 4 + r;
        float ig = sigf(acc[0][mt][r]);
        float fg = sigf(acc[1][mt][r]);
        float gg = tanhfast(acc[2][mt][r]);
        float og = sigf(acc[3][mt][r]);
        float c2 = fg * cst[ix] + ig * gg;
        cst[ix] = c2;
        hv[ix] = og * tanhfast(c2);
      }

    // ---- wave-local LDS transpose: [b][col] tile, then 8B-aligned publish
    #pragma unroll
    for (int mt = 0; mt < 2; ++mt)
      #pragma unroll
      for (int r = 0; r < 4; ++r)
        hl[(q4 * 4 + r + mt * 16) * 24 + l15] = f2bf(hv[mt * 4 + r]);
    // lane reads 16B contiguous of row rb (cols j0w + rh*8 .. +7); wave-local,
    // ordered by lgkmcnt (no barrier needed: single wave).
    ull_t plo = *(const ull_t*)&hl[rb * 24 + rh * 8];
    ull_t phi = *(const ull_t*)&hl[rb * 24 + rh * 8 + 4];
    ull_t* dst = (ull_t*)(hb_d + (t & 1) * 8192 + (size_t)rb * 256 + j0w + rh * 8);
    st_ull(dst, plo);
    st_ull(dst + 1, phi);
    // drain THIS wave's publish stores, then tag (relaxed; no fence)
    asm volatile("s_waitcnt vmcnt(0)" ::: "memory");
    if (l == 0) st_u32(fl + widx, (unsigned)(t + 1));

    // ---- outh (non-temporal, off critical path)
    float* op = outh + (size_t)(s * 32) * 512 + d * 256 + j0w + l15;
    #pragma unroll
    for (int mt = 0; mt < 2; ++mt)
      #pragma unroll
      for (int r = 0; r < 4; ++r)
        __builtin_nontemporal_store(hv[mt * 4 + r], op + (size_t)(q4 * 4 + r + mt * 16) * 512);
  }
}

// ---------------------------------------------------------------- K5: emit GEMM (tiny)
__global__ __launch_bounds__(64) void k5_emit(
    const float* __restrict__ outh, const float* __restrict__ eW,
    const float* __restrict__ eb, float* __restrict__ em) {
  int row = blockIdx.x;
  int t = threadIdx.x;
  if (t < TT) {
    const float4* o4 = (const float4*)(outh + (size_t)row * 512);
    const float4* w4 = (const float4*)(eW + (size_t)t * 512);
    float acc = 0.f;
    #pragma unroll 16
    for (int k = 0; k < 128; ++k) {
      float4 a = o4[k], bq = w4[k];
      acc += a.x * bq.x + a.y * bq.y + a.z * bq.z + a.w * bq.w;
    }
    em[row * TT + t] = acc + eb[t];
  }
}

// ---------------------------------------------------------------- K6: CRF NLL (32 independent batches)
__global__ __launch_bounds__(64) void k6_crf(
    const int* __restrict__ sentence, const int* __restrict__ tags,
    const float* __restrict__ em, const float* __restrict__ trans,
    const float* __restrict__ startv, const float* __restrict__ endv,
    float* __restrict__ outp) {
  int b = blockIdx.x;
  int j = threadIdx.x;
  __shared__ float ash[TT];
  __shared__ float red[TT];
  float tc[TT];
  float alpha = 0.f;
  if (j < TT) {
    #pragma unroll
    for (int i = 0; i < TT; ++i) tc[i] = trans[i * TT + j];
    alpha = startv[j] + em[(0 * BB + b) * TT + j];
  }
  for (int s = 1; s < SS; ++s) {
    if (j < TT) ash[j] = alpha;
    __syncthreads();
    int m = (sentence[s * BB + b] != 1) ? 1 : 0;
    if (j < TT) {
      float mx = -1e30f;
      #pragma unroll
      for (int i = 0; i < TT; ++i) mx = fmaxf(mx, ash[i] + tc[i]);
      float sum = 0.f;
      #pragma unroll
      for (int i = 0; i < TT; ++i) sum += __expf(ash[i] + tc[i] - mx);
      float nxt = mx + __logf(sum) + em[(s * BB + b) * TT + j];
      if (m) alpha = nxt;
    }
    __syncthreads();
  }
  if (j < TT) red[j] = alpha + endv[j];
  __syncthreads();
  if (j == 0) {
    float mx = -1e30f;
    for (int i = 0; i < TT; ++i) mx = fmaxf(mx, red[i]);
    float sum = 0.f;
    for (int i = 0; i < TT; ++i) sum += __expf(red[i] - mx);
    float den = mx + __logf(sum);
    int prev = tags[0 * BB + b];
    float num = startv[prev] + em[(0 * BB + b) * TT + prev];
    for (int s = 1; s < SS; ++s) {
      int tg = tags[s * BB + b];
      if (sentence[s * BB + b] != 1) {
        num += trans[prev * TT + tg] + em[(s * BB + b) * TT + tg];
        prev = tg;
      }
    }
    num += endv[prev];
    atomicAdd(outp, den - num);
  }
}

// ---------------------------------------------------------------- launcher
extern "C" void kernel_launch(void* const* d_in, const int* in_sizes, int n_in,
                              void* d_out, int out_size, void* d_ws, size_t ws_size,
                              hipStream_t stream) {
  (void)in_sizes; (void)n_in; (void)out_size; (void)ws_size;
  const int*   sentence = (const int*)d_in[0];
  const int*   charidx  = (const int*)d_in[1];
  const int*   tags     = (const int*)d_in[2];
  const float* Wwe   = (const float*)d_in[3];
  const float* Wce   = (const float*)d_in[4];
  const float* cWihF = (const float*)d_in[5];
  const float* cWhhF = (const float*)d_in[6];
  const float* cbF   = (const float*)d_in[7];
  const float* wWihF = (const float*)d_in[8];
  const float* wWhhF = (const float*)d_in[9];
  const float* wbF   = (const float*)d_in[10];
  const float* cWihB = (const float*)d_in[11];
  const float* cWhhB = (const float*)d_in[12];
  const float* cbB   = (const float*)d_in[13];
  const float* wWihB = (const float*)d_in[14];
  const float* wWhhB = (const float*)d_in[15];
  const float* wbB   = (const float*)d_in[16];
  const float* eW    = (const float*)d_in[17];
  const float* eb    = (const float*)d_in[18];
  const float* trans = (const float*)d_in[19];
  const float* startv= (const float*)d_in[20];
  const float* endv  = (const float*)d_in[21];

  char* ws = (char*)d_ws;
  unsigned int*   flags = (unsigned int*)(ws + 0);        //     512 B
  float*          ihv   = (float*)(ws + 512);             //  204800 B
  float*          x     = (float*)(ws + 205312);          // 6291456 B
  float*          wg    = (float*)(ws + 6496768);         // 33554432 B
  unsigned short* hbuf  = (unsigned short*)(ws + 40051200); // 65536 B
  float*          outh  = (float*)(ws + 40116736);        // 8388608 B
  float*          em    = (float*)(ws + 48505344);        //  278528 B
  // total ws usage: 48,783,872 B

  hipMemsetAsync(flags, 0, 512, stream);
  hipMemsetAsync(d_out, 0, sizeof(float), stream);

  k0_ihvocab<<<200, 256, 0, stream>>>(Wce, cWihF, cbF, cWihB, cbB, ihv);
  k1_char<<<512, 256, 0, stream>>>(charidx, cWhhF, cWhhB, ihv, x);
  k2_we<<<4096, 64, 0, stream>>>(sentence, Wwe, x);
  k3_ihgemm<<<dim3(16, 32), 256, 0, stream>>>(x, wWihF, wbF, wWihB, wbB, wg);
  k4_word<<<32, 64, 0, stream>>>(wWhhF, wWhhB, wg, outh, hbuf, flags);
  k5_emit<<<4096, 64, 0, stream>>>(outh, eW, eb, em);
  k6_crf<<<32, 64, 0, stream>>>(sentence, tags, em, trans, startv, endv, (float*)d_out);
}

// Round 9
// 954.925 us; speedup vs baseline: 1.7698x; 1.0645x over previous
//
#include <hip/hip_runtime.h>
#include <math.h>

#define SS 128
#define BB 32
#define CC 16
#define DW 256
#define DC 64
#define HC 128
#define KX 384   // DW + HC
#define TT 17

typedef __attribute__((ext_vector_type(8))) short bf16x8;
typedef __attribute__((ext_vector_type(4))) float f32x4;
typedef unsigned long long ull_t;

__device__ __forceinline__ float sigf(float x) { return 1.0f / (1.0f + __expf(-x)); }
__device__ __forceinline__ float tanhfast(float x) {
  float xc = fminf(fmaxf(x, -15.f), 15.f);
  float e = __expf(2.f * xc);
  return (e - 1.f) / (e + 1.f);
}
__device__ __forceinline__ unsigned short f2bf(float x) {
  unsigned int u = __float_as_uint(x);
  u += 0x7FFF + ((u >> 16) & 1);
  return (unsigned short)(u >> 16);
}
// Relaxed agent-scope atomics ONLY (native 32/64-bit, cache-bypassing; no fences).
__device__ __forceinline__ unsigned ld_u32(const unsigned* p) {
  return __hip_atomic_load(p, __ATOMIC_RELAXED, __HIP_MEMORY_SCOPE_AGENT);
}
__device__ __forceinline__ void st_u32(unsigned* p, unsigned v) {
  __hip_atomic_store(p, v, __ATOMIC_RELAXED, __HIP_MEMORY_SCOPE_AGENT);
}
__device__ __forceinline__ ull_t ld_ull(const ull_t* p) {
  return __hip_atomic_load(p, __ATOMIC_RELAXED, __HIP_MEMORY_SCOPE_AGENT);
}
__device__ __forceinline__ void st_ull(ull_t* p, ull_t v) {
  __hip_atomic_store(p, v, __ATOMIC_RELAXED, __HIP_MEMORY_SCOPE_AGENT);
}

// ---------------------------------------------------------------- K0: char ih vocab table
__global__ __launch_bounds__(256) void k0_ihvocab(
    const float* __restrict__ Wce,
    const float* __restrict__ WihF, const float* __restrict__ bF,
    const float* __restrict__ WihB, const float* __restrict__ bB,
    float* __restrict__ ihv) {
  int blk = blockIdx.x;          // 0..199
  int d = blk / 100, v = blk % 100;
  const float* Wih = d ? WihB : WihF;
  const float* bb  = d ? bB   : bF;
  __shared__ float ce[DC];
  if (threadIdx.x < DC) ce[threadIdx.x] = Wce[v * DC + threadIdx.x];
  __syncthreads();
  int g = threadIdx.x;
  float acc = bb[g];
  #pragma unroll 16
  for (int k = 0; k < DC; ++k) acc += ce[k] * Wih[g * DC + k];
  ihv[(d * 100 + v) * 256 + g] = acc;
}

// ---------------------------------------------------------------- K1: char BiLSTM (per-chain, no global sync)
__global__ __launch_bounds__(256) void k1_char(
    const int* __restrict__ charidx,   // (B,S,C)
    const float* __restrict__ WhhF, const float* __restrict__ WhhB,
    const float* __restrict__ ihv,     // (2,100,256)
    float* __restrict__ x)             // (4096, 384)
{
  int blk = blockIdx.x;
  int d = blk >> 8;
  int n0 = (blk & 255) * 16;
  const float* Whh = d ? WhhB : WhhF;

  __shared__ float Wl[256 * 64];
  __shared__ float hl[16 * 68];

  for (int i = threadIdx.x; i < 256 * 64; i += 256) {
    int g = i >> 6, k = i & 63;
    Wl[g * 64 + (((k >> 2) ^ (g & 15)) << 2) + (k & 3)] = Whh[i];
  }
  __syncthreads();

  int hh = threadIdx.x & 63;
  int ng = threadIdx.x >> 6;
  float c[4] = {0.f, 0.f, 0.f, 0.f};
  float h[4] = {0.f, 0.f, 0.f, 0.f};
  int bb_[4], ss_[4];
  #pragma unroll
  for (int m = 0; m < 4; ++m) {
    int n = n0 + ng + 4 * m;
    bb_[m] = n >> 7; ss_[m] = n & 127;
  }

  for (int t = 0; t < CC; ++t) {
    int cpos = d ? (CC - 1 - t) : t;
    float acc[4][4];
    #pragma unroll
    for (int m = 0; m < 4; ++m) {
      int v = charidx[bb_[m] * (SS * CC) + ss_[m] * CC + cpos];
      const float* base = ihv + (d * 100 + v) * 256 + hh;
      acc[m][0] = base[0]; acc[m][1] = base[64]; acc[m][2] = base[128]; acc[m][3] = base[192];
    }
    if (t > 0) {
      #pragma unroll 4
      for (int k = 0; k < 64; k += 4) {
        int kc = k >> 2;
        float4 w4[4];
        #pragma unroll
        for (int q = 0; q < 4; ++q)
          w4[q] = *(const float4*)&Wl[(q * 64 + hh) * 64 + ((kc ^ (hh & 15)) << 2)];
        #pragma unroll
        for (int m = 0; m < 4; ++m) {
          float4 h4 = *(const float4*)&hl[(ng + 4 * m) * 68 + k];
          #pragma unroll
          for (int q = 0; q < 4; ++q)
            acc[m][q] += h4.x * w4[q].x + h4.y * w4[q].y + h4.z * w4[q].z + h4.w * w4[q].w;
        }
      }
      __syncthreads();
    }
    #pragma unroll
    for (int m = 0; m < 4; ++m) {
      float ig = sigf(acc[m][0]);
      float fg = sigf(acc[m][1]);
      float gg = tanhfast(acc[m][2]);
      float og = sigf(acc[m][3]);
      c[m] = fg * c[m] + ig * gg;
      h[m] = og * tanhfast(c[m]);
      hl[(ng + 4 * m) * 68 + hh] = h[m];
    }
    __syncthreads();
  }
  #pragma unroll
  for (int m = 0; m < 4; ++m) {
    int row = ss_[m] * BB + bb_[m];
    x[row * KX + d * 64 + hh] = h[m];
  }
}

// ---------------------------------------------------------------- K2: word embedding gather
__global__ __launch_bounds__(64) void k2_we(
    const int* __restrict__ sentence, const float* __restrict__ Wwe,
    float* __restrict__ x) {
  int row = blockIdx.x;
  int idx = sentence[row];
  const float4* src = (const float4*)(Wwe + (size_t)idx * DW);
  float4* dst = (float4*)(x + (size_t)row * KX + HC);
  dst[threadIdx.x] = src[threadIdx.x];
}

// ---------------------------------------------------------------- KCV: convert x and Wih to bf16 (packed row-major)
// xb: (4096,384) bf16; wb: (2048,384) bf16 (rows 0..1023 = F, 1024..2047 = B).
// Octet-indexed grid-stride: 294912 octets total = 1152 blocks x 256.
__global__ __launch_bounds__(256) void kcv(
    const float* __restrict__ x,
    const float* __restrict__ WihF, const float* __restrict__ WihB,
    unsigned short* __restrict__ xb, unsigned short* __restrict__ wb) {
  int i = blockIdx.x * 256 + threadIdx.x;
  const float* src; unsigned short* dst; int off;
  if (i < 196608)      { src = x;    dst = xb;              off = i; }
  else if (i < 245760) { src = WihF; dst = wb;              off = i - 196608; }
  else                 { src = WihB; dst = wb + 1024 * 384; off = i - 245760; }
  float4 a = *(const float4*)(src + (size_t)off * 8);
  float4 b = *(const float4*)(src + (size_t)off * 8 + 4);
  bf16x8 o;
  o[0] = (short)f2bf(a.x); o[1] = (short)f2bf(a.y);
  o[2] = (short)f2bf(a.z); o[3] = (short)f2bf(a.w);
  o[4] = (short)f2bf(b.x); o[5] = (short)f2bf(b.y);
  o[6] = (short)f2bf(b.z); o[7] = (short)f2bf(b.w);
  *(bf16x8*)(dst + (size_t)off * 8) = o;
}

// ---------------------------------------------------------------- K3M: word ih GEMM, bf16 MFMA
// C(4096 x 2048) = xb(4096,384) @ wb(2048,384)^T + bias -> wg[d][m][g].
// Grid (16,32): n0 = bx*128 (d = n0>>10, one d per block), m0 = by*128.
// 256 thr = 4 waves in 2x2; wave owns 64x64; 16x16x32 MFMA, K-loop 12.
// LDS rows padded to 40 shorts (80 B): bank stride 20 -> worst 2-way (free).
__global__ __launch_bounds__(256) void k3m(
    const unsigned short* __restrict__ xb, const unsigned short* __restrict__ wb,
    const float* __restrict__ bF, const float* __restrict__ bB,
    float* __restrict__ wg) {
  const int n0 = blockIdx.x * 128;
  const int m0 = blockIdx.y * 128;
  const int d  = n0 >> 10;
  const int gb0 = n0 & 1023;
  const float* bias = d ? bB : bF;

  __shared__ unsigned short Ab[128 * 40];
  __shared__ unsigned short Bb[128 * 40];

  const int tid = threadIdx.x;
  const int l = tid & 63, w = tid >> 6;
  const int wm = w >> 1, wn = w & 1;
  const int l15 = l & 15, q4 = l >> 4;
  const int sr = tid >> 1, shf = tid & 1;   // staging row / 32B-half

  f32x4 acc[4][4];
  #pragma unroll
  for (int mr = 0; mr < 4; ++mr)
    #pragma unroll
    for (int nr = 0; nr < 4; ++nr)
      acc[mr][nr] = (f32x4){0.f, 0.f, 0.f, 0.f};

  for (int kt = 0; kt < 12; ++kt) {
    __syncthreads();
    {
      const bf16x8* sA = (const bf16x8*)(xb + (size_t)(m0 + sr) * KX + kt * 32 + shf * 16);
      const bf16x8* sB = (const bf16x8*)(wb + (size_t)(n0 + sr) * KX + kt * 32 + shf * 16);
      bf16x8 a0 = sA[0], a1 = sA[1];
      bf16x8 b0 = sB[0], b1 = sB[1];
      *(bf16x8*)&Ab[sr * 40 + shf * 16]     = a0;
      *(bf16x8*)&Ab[sr * 40 + shf * 16 + 8] = a1;
      *(bf16x8*)&Bb[sr * 40 + shf * 16]     = b0;
      *(bf16x8*)&Bb[sr * 40 + shf * 16 + 8] = b1;
    }
    __syncthreads();
    bf16x8 Afr[4], Bfr[4];
    #pragma unroll
    for (int mr = 0; mr < 4; ++mr)
      Afr[mr] = *(const bf16x8*)&Ab[(wm * 64 + mr * 16 + l15) * 40 + q4 * 8];
    #pragma unroll
    for (int nr = 0; nr < 4; ++nr)
      Bfr[nr] = *(const bf16x8*)&Bb[(wn * 64 + nr * 16 + l15) * 40 + q4 * 8];
    #pragma unroll
    for (int mr = 0; mr < 4; ++mr)
      #pragma unroll
      for (int nr = 0; nr < 4; ++nr)
        acc[mr][nr] = __builtin_amdgcn_mfma_f32_16x16x32_bf16(Afr[mr], Bfr[nr], acc[mr][nr], 0, 0, 0);
  }

  // C/D layout: col = lane&15, row = (lane>>4)*4 + reg  [guide m89]
  #pragma unroll
  for (int nr = 0; nr < 4; ++nr) {
    int gcol = gb0 + wn * 64 + nr * 16 + l15;
    float bv = bias[gcol];
    #pragma unroll
    for (int mr = 0; mr < 4; ++mr) {
      int mrow = m0 + wm * 64 + mr * 16 + q4 * 4;
      float* dst = wg + ((size_t)(d * 4096 + mrow)) * 1024 + gcol;
      #pragma unroll
      for (int r = 0; r < 4; ++r)
        dst[(size_t)r * 1024] = acc[mr][nr][r] + bv;
    }
  }
}

// ---------------------------------------------------------------- K4: word BiLSTM recurrence (round-0 global-flag design, 523us proven)
// 32 WGs x 64 threads (1 wave each), 16 waves per direction. Wave widx owns
// h-cols j0w..j0w+15 (x4 gate blocks). Whh in 128 VGPRs as bf16 B-frags
// (64-thr blocks get a >=144 VGPR budget; 512-thr blocks are pinned at 128
// -- rounds 2-7 evidence). ~3 coherence RTs/step is the measured floor for
// cross-CU sync (rounds 0-8: 520-528us, 4 independent measurements).
__global__ __launch_bounds__(64, 1) void k4_word(
    const float* __restrict__ WhhF, const float* __restrict__ WhhB,
    const float* __restrict__ wg,           // (2,4096,1024) f32
    float* __restrict__ outh,               // (4096,512) f32
    unsigned short* __restrict__ hbuf,      // (2 dir, 2 parity, 32 b, 256 k) bf16
    unsigned int* __restrict__ flags) {     // per dir: 16 tags at dir*16
  const int blk = blockIdx.x;               // 0..31
  const int d = blk >> 4, widx = blk & 15;
  const int l = threadIdx.x;                // 0..63
  const int l15 = l & 15, q4 = l >> 4;
  const int j0w = widx * 16;
  const float* __restrict__ Whh = d ? WhhB : WhhF;
  unsigned short* hb_d = hbuf + d * 16384;  // 2 parities * 8192
  unsigned int* fl = flags + d * 16;

  __shared__ unsigned short hl[32 * 24];    // per-wave transpose tile, row stride 48B

  // ---- Whh B-fragments resident: lane holds B[k=ks*32+q4*8+j][n=l15]
  bf16x8 Bf[4][8];
  #pragma unroll
  for (int q = 0; q < 4; ++q) {
    const float* wr = Whh + (size_t)(q * 256 + j0w + l15) * 256 + q4 * 8;
    #pragma unroll
    for (int ks = 0; ks < 8; ++ks) {
      float4 lo = *(const float4*)(wr + ks * 32);
      float4 hi = *(const float4*)(wr + ks * 32 + 4);
      bf16x8 f;
      f[0] = (short)f2bf(lo.x); f[1] = (short)f2bf(lo.y);
      f[2] = (short)f2bf(lo.z); f[3] = (short)f2bf(lo.w);
      f[4] = (short)f2bf(hi.x); f[5] = (short)f2bf(hi.y);
      f[6] = (short)f2bf(hi.z); f[7] = (short)f2bf(hi.w);
      Bf[q][ks] = f;
    }
  }

  float cst[8];
  #pragma unroll
  for (int i = 0; i < 8; ++i) cst[i] = 0.f;

  const int rb = l >> 1;          // transpose-read row (batch) 0..31
  const int rh = l & 1;           // transpose-read half-chunk

  for (int t = 0; t < SS; ++t) {
    const int s = d ? (SS - 1 - t) : t;

    // ---- ih gates into MFMA C-layout (issued before the wait; overlaps poll)
    f32x4 acc[4][2];
    const float* wgs = wg + ((size_t)d * 4096 + (size_t)s * 32) * 1024 + j0w + l15;
    #pragma unroll
    for (int q = 0; q < 4; ++q)
      #pragma unroll
      for (int mt = 0; mt < 2; ++mt)
        #pragma unroll
        for (int r = 0; r < 4; ++r)
          acc[q][mt][r] = wgs[(size_t)(q4 * 4 + r + mt * 16) * 1024 + q * 256];

    if (t > 0) {
      // ---- wait for all 16 producer waves of this direction (relaxed polls)
      for (;;) {
        unsigned tg = ld_u32(fl + l15);
        if (__all((int)(tg >= (unsigned)t))) break;
        __builtin_amdgcn_s_sleep(1);
      }

      // ---- A-fragments of h_{t-1}: cache-bypassing 8B loads
      const unsigned short* hp = hb_d + ((t - 1) & 1) * 8192 + q4 * 8;
      bf16x8 Af[2][8];
      #pragma unroll
      for (int mt = 0; mt < 2; ++mt)
        #pragma unroll
        for (int ks = 0; ks < 8; ++ks) {
          const ull_t* p = (const ull_t*)(hp + (size_t)(l15 + mt * 16) * 256 + ks * 32);
          union { ull_t u[2]; bf16x8 v; } cvt;
          cvt.u[0] = ld_ull(p);
          cvt.u[1] = ld_ull(p + 1);
          Af[mt][ks] = cvt.v;
        }
      #pragma unroll
      for (int q = 0; q < 4; ++q)
        #pragma unroll
        for (int mt = 0; mt < 2; ++mt) {
          f32x4 c = acc[q][mt];
          #pragma unroll
          for (int ks = 0; ks < 8; ++ks)
            c = __builtin_amdgcn_mfma_f32_16x16x32_bf16(Af[mt][ks], Bf[q][ks], c, 0, 0, 0);
          acc[q][mt] = c;
        }
    }

    // ---- activations; lane owns (b = q4*4+r+mt*16, col = j0w+l15)
    float hv[8];
    #pragma unroll
    for (int mt = 0; mt < 2; ++mt)
      #pragma unroll
      for (int r = 0; r < 4; ++r) {
        int ix = mt * 4 + r;
        float ig = sigf(acc[0][mt][r]);
        float fg = sigf(acc[1][mt][r]);
        float gg = tanhfast(acc[2][mt][r]);
        float og = sigf(acc[3][mt][r]);
        float c2 = fg * cst[ix] + ig * gg;
        cst[ix] = c2;
        hv[ix] = og * tanhfast(c2);
      }

    // ---- wave-local LDS transpose: [b][col] tile, then 8B-aligned publish
    #pragma unroll
    for (int mt = 0; mt < 2; ++mt)
      #pragma unroll
      for (int r = 0; r < 4; ++r)
        hl[(q4 * 4 + r + mt * 16) * 24 + l15] = f2bf(hv[mt * 4 + r]);
    ull_t plo = *(const ull_t*)&hl[rb * 24 + rh * 8];
    ull_t phi = *(const ull_t*)&hl[rb * 24 + rh * 8 + 4];
    ull_t* dst = (ull_t*)(hb_d + (t & 1) * 8192 + (size_t)rb * 256 + j0w + rh * 8);
    st_ull(dst, plo);
    st_ull(dst + 1, phi);
    // drain THIS wave's publish stores, then tag (relaxed; no fence)
    asm volatile("s_waitcnt vmcnt(0)" ::: "memory");
    if (l == 0) st_u32(fl + widx, (unsigned)(t + 1));

    // ---- outh (non-temporal, off critical path)
    float* op = outh + (size_t)(s * 32) * 512 + d * 256 + j0w + l15;
    #pragma unroll
    for (int mt = 0; mt < 2; ++mt)
      #pragma unroll
      for (int r = 0; r < 4; ++r)
        __builtin_nontemporal_store(hv[mt * 4 + r], op + (size_t)(q4 * 4 + r + mt * 16) * 512);
  }
}

// ---------------------------------------------------------------- K5: emit GEMM (tiny)
__global__ __launch_bounds__(64) void k5_emit(
    const float* __restrict__ outh, const float* __restrict__ eW,
    const float* __restrict__ eb, float* __restrict__ em) {
  int row = blockIdx.x;
  int t = threadIdx.x;
  if (t < TT) {
    const float4* o4 = (const float4*)(outh + (size_t)row * 512);
    const float4* w4 = (const float4*)(eW + (size_t)t * 512);
    float acc = 0.f;
    #pragma unroll 16
    for (int k = 0; k < 128; ++k) {
      float4 a = o4[k], bq = w4[k];
      acc += a.x * bq.x + a.y * bq.y + a.z * bq.z + a.w * bq.w;
    }
    em[row * TT + t] = acc + eb[t];
  }
}

// ---------------------------------------------------------------- K6: CRF NLL (32 independent batches)
__global__ __launch_bounds__(64) void k6_crf(
    const int* __restrict__ sentence, const int* __restrict__ tags,
    const float* __restrict__ em, const float* __restrict__ trans,
    const float* __restrict__ startv, const float* __restrict__ endv,
    float* __restrict__ outp) {
  int b = blockIdx.x;
  int j = threadIdx.x;
  __shared__ float ash[TT];
  __shared__ float red[TT];
  float tc[TT];
  float alpha = 0.f;
  if (j < TT) {
    #pragma unroll
    for (int i = 0; i < TT; ++i) tc[i] = trans[i * TT + j];
    alpha = startv[j] + em[(0 * BB + b) * TT + j];
  }
  for (int s = 1; s < SS; ++s) {
    if (j < TT) ash[j] = alpha;
    __syncthreads();
    int m = (sentence[s * BB + b] != 1) ? 1 : 0;
    if (j < TT) {
      float mx = -1e30f;
      #pragma unroll
      for (int i = 0; i < TT; ++i) mx = fmaxf(mx, ash[i] + tc[i]);
      float sum = 0.f;
      #pragma unroll
      for (int i = 0; i < TT; ++i) sum += __expf(ash[i] + tc[i] - mx);
      float nxt = mx + __logf(sum) + em[(s * BB + b) * TT + j];
      if (m) alpha = nxt;
    }
    __syncthreads();
  }
  if (j < TT) red[j] = alpha + endv[j];
  __syncthreads();
  if (j == 0) {
    float mx = -1e30f;
    for (int i = 0; i < TT; ++i) mx = fmaxf(mx, red[i]);
    float sum = 0.f;
    for (int i = 0; i < TT; ++i) sum += __expf(red[i] - mx);
    float den = mx + __logf(sum);
    int prev = tags[0 * BB + b];
    float num = startv[prev] + em[(0 * BB + b) * TT + prev];
    for (int s = 1; s < SS; ++s) {
      int tg = tags[s * BB + b];
      if (sentence[s * BB + b] != 1) {
        num += trans[prev * TT + tg] + em[(s * BB + b) * TT + tg];
        prev = tg;
      }
    }
    num += endv[prev];
    atomicAdd(outp, den - num);
  }
}

// ---------------------------------------------------------------- launcher
extern "C" void kernel_launch(void* const* d_in, const int* in_sizes, int n_in,
                              void* d_out, int out_size, void* d_ws, size_t ws_size,
                              hipStream_t stream) {
  (void)in_sizes; (void)n_in; (void)out_size; (void)ws_size;
  const int*   sentence = (const int*)d_in[0];
  const int*   charidx  = (const int*)d_in[1];
  const int*   tags     = (const int*)d_in[2];
  const float* Wwe   = (const float*)d_in[3];
  const float* Wce   = (const float*)d_in[4];
  const float* cWihF = (const float*)d_in[5];
  const float* cWhhF = (const float*)d_in[6];
  const float* cbF   = (const float*)d_in[7];
  const float* wWihF = (const float*)d_in[8];
  const float* wWhhF = (const float*)d_in[9];
  const float* wbF   = (const float*)d_in[10];
  const float* cWihB = (const float*)d_in[11];
  const float* cWhhB = (const float*)d_in[12];
  const float* cbB   = (const float*)d_in[13];
  const float* wWihB = (const float*)d_in[14];
  const float* wWhhB = (const float*)d_in[15];
  const float* wbB   = (const float*)d_in[16];
  const float* eW    = (const float*)d_in[17];
  const float* eb    = (const float*)d_in[18];
  const float* trans = (const float*)d_in[19];
  const float* startv= (const float*)d_in[20];
  const float* endv  = (const float*)d_in[21];

  char* ws = (char*)d_ws;
  unsigned int*   flags = (unsigned int*)(ws + 0);        //     512 B
  float*          ihv   = (float*)(ws + 512);             //  204800 B
  float*          x     = (float*)(ws + 205312);          // 6291456 B
  float*          wg    = (float*)(ws + 6496768);         // 33554432 B
  unsigned short* hbuf  = (unsigned short*)(ws + 40051200); // 65536 B
  float*          outh  = (float*)(ws + 40116736);        // 8388608 B
  float*          em    = (float*)(ws + 48505344);        //  278528 B
  // xb (3,145,728 B) + wb (1,572,864 B) alias the outh region: outh is only
  // written by k4 (after k3m has consumed xb/wb) and read by k5.
  unsigned short* xb = (unsigned short*)(ws + 40116736);
  unsigned short* wb = (unsigned short*)(ws + 40116736 + 3145728);
  // total ws usage: 48,783,872 B (unchanged)

  hipMemsetAsync(flags, 0, 512, stream);
  hipMemsetAsync(d_out, 0, sizeof(float), stream);

  k0_ihvocab<<<200, 256, 0, stream>>>(Wce, cWihF, cbF, cWihB, cbB, ihv);
  k1_char<<<512, 256, 0, stream>>>(charidx, cWhhF, cWhhB, ihv, x);
  k2_we<<<4096, 64, 0, stream>>>(sentence, Wwe, x);
  kcv<<<1152, 256, 0, stream>>>(x, wWihF, wWihB, xb, wb);
  k3m<<<dim3(16, 32), 256, 0, stream>>>(xb, wb, wbF, wbB, wg);
  k4_word<<<32, 64, 0, stream>>>(wWhhF, wWhhB, wg, outh, hbuf, flags);
  k5_emit<<<4096, 64, 0, stream>>>(outh, eW, eb, em);
  k6_crf<<<32, 64, 0, stream>>>(sentence, tags, em, trans, startv, endv, (float*)d_out);
}